// Round 22
// baseline (225.523 us; speedup 1.0000x reference)
//
#include <hip/hip_runtime.h>
#include <math.h>

#define A_TOTAL 261120
#define B_BATCH 8
#define K_PER_LVL 1000
#define K_TOTAL 4000
#define NSORT 4096
#define POST_N 1000
#define NEGV -1e30f
#define BBOX_CLIP 4.135166556742356f
#define CAND_CAP 3072

typedef unsigned long long u64;

__device__ __forceinline__ unsigned sortable(float f) {
    unsigned u = __float_as_uint(f);
    return (u & 0x80000000u) ? ~u : (u | 0x80000000u);
}

__device__ __forceinline__ float unsortable(unsigned u) {
    return (u & 0x80000000u) ? __uint_as_float(u & 0x7FFFFFFFu) : __uint_as_float(~u);
}

// Parallel "find threshold bin from top" over hist[NB]; all 512 threads call.
// Result: s_res[0]=T (bin), s_res[1]=G (count strictly above bin T).
template<int NB>
__device__ __forceinline__ void radix_sel(unsigned* hist, unsigned need,
                                          unsigned* s_res, unsigned* swsum) {
    const int per = NB >> 9;
    int tid = threadIdx.x;
    unsigned vals[per];
    unsigned part = 0;
    #pragma unroll
    for (int e = 0; e < per; ++e) {
        unsigned v = hist[NB - 1 - (tid * per + e)];   // high bins first
        vals[e] = v; part += v;
    }
    int lane = tid & 63, wv = tid >> 6;
    unsigned x = part;
    #pragma unroll
    for (int d = 1; d < 64; d <<= 1) {
        unsigned y = __shfl_up(x, d);
        if (lane >= d) x += y;
    }
    if (lane == 63) swsum[wv] = x;
    __syncthreads();
    unsigned woff = 0;
    for (int w = 0; w < wv; ++w) woff += swsum[w];
    unsigned run = woff + x - part;    // exclusive prefix (count in bins above)
    #pragma unroll
    for (int e = 0; e < per; ++e) {
        unsigned c = vals[e];
        if (run < need && run + c >= need) {
            s_res[0] = (unsigned)(NB - 1 - (tid * per + e));
            s_res[1] = run;
        }
        run += c;
    }
    __syncthreads();
}

// ============ FAST PATH ============

// K1a: 512 blocks (b*64 + chunk). Per-chunk LDS hist -> global hist[b][lvl].
__global__ __launch_bounds__(512) void topk_hist(const float* __restrict__ obj,
                                                 unsigned* __restrict__ hist) {
    int blk = blockIdx.x;
    int b = blk >> 6, c = blk & 63;
    int lvl = c < 48 ? 0 : c < 60 ? 1 : c < 63 ? 2 : 3;
    const float4* src = (const float4*)(obj + (size_t)b * A_TOTAL + (size_t)c * 4096);
    int n4c = (c == 63) ? 768 : 1024;
    __shared__ unsigned h[2048];
    int tid = threadIdx.x;
    for (int i = tid; i < 2048; i += 512) h[i] = 0;
    __syncthreads();
    for (int i4 = tid; i4 < n4c; i4 += 512) {
        float4 v = src[i4];
        atomicAdd(&h[sortable(v.x) >> 21], 1u);
        atomicAdd(&h[sortable(v.y) >> 21], 1u);
        atomicAdd(&h[sortable(v.z) >> 21], 1u);
        atomicAdd(&h[sortable(v.w) >> 21], 1u);
    }
    __syncthreads();
    unsigned* gh = hist + ((size_t)(b * 4 + lvl) << 11);
    for (int i = tid; i < 2048; i += 512) {
        unsigned cc = h[i];
        if (cc) atomicAdd(&gh[i], cc);
    }
}

// K1b: 32 blocks (b,lvl). Threshold bin T1 from hist.
__global__ __launch_bounds__(512) void topk_thresh(const unsigned* __restrict__ hist,
                                                   unsigned* __restrict__ t1arr) {
    __shared__ unsigned h[2048];
    __shared__ unsigned s_res[2];
    __shared__ unsigned swsum[8];
    int tid = threadIdx.x;
    for (int i = tid; i < 2048; i += 512) h[i] = hist[((size_t)blockIdx.x << 11) + i];
    __syncthreads();
    radix_sel<2048>(h, K_PER_LVL, s_res, swsum);
    if (tid == 0) t1arr[blockIdx.x] = s_res[0];
}

// K1c: 512 blocks (topk_hist grid). Scan data: >T1 -> sel (global counter);
// ==T1 -> gcand (global counter, capped). Order within sel is irrelevant:
// final sort key ties break by unique anchor index, not slot.
__global__ __launch_bounds__(512) void topk_scan(const float* __restrict__ obj,
                                                 const unsigned* __restrict__ t1arr,
                                                 int* __restrict__ sel,
                                                 unsigned* __restrict__ gcnt,
                                                 unsigned* __restrict__ geq,
                                                 u64* __restrict__ gcand) {
    int blk = blockIdx.x;
    int b = blk >> 6, c = blk & 63;
    int lvl = c < 48 ? 0 : c < 60 ? 1 : c < 63 ? 2 : 3;
    const int offs[4] = {0, 196608, 245760, 258048};
    int off = offs[lvl];
    const float4* src = (const float4*)(obj + (size_t)b * A_TOTAL + (size_t)c * 4096);
    int n4c = (c == 63) ? 768 : 1024;
    int bl = b * 4 + lvl;
    unsigned T1 = t1arr[bl];
    int* out = sel + (size_t)bl * K_PER_LVL;
    u64* cand = gcand + (size_t)bl * CAND_CAP;
    int tid = threadIdx.x;
    int lbase = c * 4096 - off;          // chunk start, level-local
    for (int i4 = tid; i4 < n4c; i4 += 512) {
        float4 v = src[i4];
        float arr[4] = {v.x, v.y, v.z, v.w};
        #pragma unroll
        for (int cc = 0; cc < 4; ++cc) {
            unsigned k = sortable(arr[cc]);
            unsigned bin = k >> 21;
            int i = lbase + 4 * i4 + cc; // level-local index
            if (bin > T1) {
                unsigned p = atomicAdd(&gcnt[bl], 1u);
                out[p] = off + i;
            } else if (bin == T1) {
                unsigned p = atomicAdd(&geq[bl], 1u);
                if (p < CAND_CAP)
                    cand[p] = (((u64)(k & 0x1FFFFFu)) << 18)
                            | (u64)(0x3FFFFu - (unsigned)i);
            }
        }
    }
}

// K1d: 32 blocks. Exact top-m of boundary-bin candidates via 3x13-bit radix
// select on 39-bit unique keys; append at out[G1..].
__global__ __launch_bounds__(512) void topk_fin(const unsigned* __restrict__ hist,
                                                const unsigned* __restrict__ geq,
                                                const u64* __restrict__ gcand,
                                                int* __restrict__ sel) {
    int bl = blockIdx.x;
    const int offs[4] = {0, 196608, 245760, 258048};
    int off = offs[bl & 3];
    __shared__ unsigned h[8192];
    __shared__ u64 cand[CAND_CAP];
    __shared__ unsigned s_res[2];
    __shared__ unsigned swsum[8];
    __shared__ unsigned s_c2;
    int tid = threadIdx.x;

    for (int i = tid; i < 2048; i += 512) h[i] = hist[((size_t)bl << 11) + i];
    if (tid == 0) s_c2 = 0;
    __syncthreads();
    radix_sel<2048>(h, K_PER_LVL, s_res, swsum);
    unsigned G1 = s_res[1];
    int E = (int)min(geq[bl], (unsigned)CAND_CAP);
    const u64* gc = gcand + (size_t)bl * CAND_CAP;
    for (int e = tid; e < E; e += 512) cand[e] = gc[e];
    __syncthreads();
    unsigned m = K_PER_LVL - G1;

    // pass A: bits 38:26
    for (int i = tid; i < 8192; i += 512) h[i] = 0;
    __syncthreads();
    for (int e = tid; e < E; e += 512) atomicAdd(&h[(unsigned)(cand[e] >> 26)], 1u);
    __syncthreads();
    radix_sel<8192>(h, m, s_res, swsum);
    unsigned TA = s_res[0], GA = s_res[1];
    // pass B: bits 25:13 among prefix TA
    for (int i = tid; i < 8192; i += 512) h[i] = 0;
    __syncthreads();
    for (int e = tid; e < E; e += 512) {
        u64 ck = cand[e];
        if ((unsigned)(ck >> 26) == TA) atomicAdd(&h[(unsigned)(ck >> 13) & 0x1FFFu], 1u);
    }
    __syncthreads();
    radix_sel<8192>(h, m - GA, s_res, swsum);
    unsigned TB = s_res[0], GB = s_res[1];
    // pass C: bits 12:0 among prefix (TA,TB)
    for (int i = tid; i < 8192; i += 512) h[i] = 0;
    __syncthreads();
    unsigned pref26 = (TA << 13) | TB;
    for (int e = tid; e < E; e += 512) {
        u64 ck = cand[e];
        if ((unsigned)(ck >> 13) == pref26) atomicAdd(&h[(unsigned)ck & 0x1FFFu], 1u);
    }
    __syncthreads();
    radix_sel<8192>(h, m - GA - GB, s_res, swsum);
    unsigned TC = s_res[0];
    u64 KSTAR = (((u64)TA) << 26) | (((u64)TB) << 13) | (u64)TC;
    int* out = sel + (size_t)bl * K_PER_LVL;
    for (int e = tid; e < E; e += 512) {
        u64 ck = cand[e];
        if (ck >= KSTAR) {
            unsigned p = atomicAdd(&s_c2, 1u);
            out[G1 + p] = off + (int)(0x3FFFFu - (unsigned)(ck & 0x3FFFFu));
        }
    }
}

// K2a: decode slot SoA to scratch + sort own 512-key segment in LDS
// (bitonic stages k=2..512; all pairs intra-segment; global-index direction).
// Grid 64: blockIdx = b*8 + seg.
__global__ __launch_bounds__(512) void decode_seg(const float* __restrict__ obj,
                                                  const float* __restrict__ deltas,
                                                  const float* __restrict__ anchors,
                                                  const int* __restrict__ sel,
                                                  u64* __restrict__ skey,
                                                  float* __restrict__ sx1, float* __restrict__ sy1,
                                                  float* __restrict__ sx2, float* __restrict__ sy2,
                                                  unsigned char* __restrict__ slv) {
    int b = blockIdx.x >> 3, seg = blockIdx.x & 7;
    int tid = threadIdx.x;
    __shared__ u64 kk[512];
    int s = (seg << 9) + tid;
    size_t base = (size_t)b * NSORT + s;

    if (s < K_TOTAL) {
        int g = sel[(size_t)b * K_TOTAL + s];
        float score = obj[(size_t)b * A_TOTAL + g];
        float4 dl = *(const float4*)(deltas + ((size_t)b * A_TOTAL + g) * 4);
        float4 an = *(const float4*)(anchors + (size_t)g * 4);
        float wa = an.z - an.x, ha = an.w - an.y;
        float cxa = an.x + 0.5f * wa, cya = an.y + 0.5f * ha;
        float dw = fminf(dl.z, BBOX_CLIP), dh = fminf(dl.w, BBOX_CLIP);
        float cx = dl.x * wa + cxa, cy = dl.y * ha + cya;
        float w = expf(dw) * wa, h = expf(dh) * ha;
        float x1 = cx - 0.5f * w, y1 = cy - 0.5f * h;
        float x2 = cx + 0.5f * w, y2 = cy + 0.5f * h;
        x1 = fminf(fmaxf(x1, 0.f), 1024.f);
        y1 = fminf(fmaxf(y1, 0.f), 1024.f);
        x2 = fminf(fmaxf(x2, 0.f), 1024.f);
        y2 = fminf(fmaxf(y2, 0.f), 1024.f);
        bool valid = (x2 - x1 >= 0.001f) && (y2 - y1 >= 0.001f) && (score >= 0.f);
        float sm = valid ? score : NEGV;
        int lv = (g >= 258048) ? 3 : (g >= 245760) ? 2 : (g >= 196608) ? 1 : 0;
        float lo = (float)lv * 1025.0f;
        sx1[base] = x1 + lo; sy1[base] = y1 + lo;
        sx2[base] = x2 + lo; sy2[base] = y2 + lo;
        slv[base] = (unsigned char)lv;
        kk[tid] = ((u64)sortable(sm) << 32)
                | ((u64)(0x3FFFFu - (unsigned)g) << 12)
                | (unsigned)s;
    } else {
        sx1[base] = 0.f; sy1[base] = 0.f; sx2[base] = 0.f; sy2[base] = 0.f;
        slv[base] = 0;
        kk[tid] = ((u64)sortable(NEGV) << 32) | (unsigned)s;
    }
    __syncthreads();

    for (int k = 2; k <= 512; k <<= 1) {
        for (int j = k >> 1; j > 0; j >>= 1) {
            int p = tid ^ j;
            if (p > tid) {
                u64 a = kk[tid], c = kk[p];
                bool up = (s & k) == 0;        // global-index direction
                if (up ? (a < c) : (a > c)) { kk[tid] = c; kk[p] = a; }
            }
            __syncthreads();
        }
    }
    skey[base] = kk[tid];
}

// K2b: merge sorted 512-segments (bitonic stages k=1024..4096, keys-only LDS),
// then gather slot SoA from scratch and emit sorted SoA + V. Grid 8.
__global__ __launch_bounds__(1024) void merge_sort(const u64* __restrict__ skey,
                                                   const float* __restrict__ sx1,
                                                   const float* __restrict__ sy1,
                                                   const float* __restrict__ sx2,
                                                   const float* __restrict__ sy2,
                                                   const unsigned char* __restrict__ slv,
                                                   float* __restrict__ gx1, float* __restrict__ gy1,
                                                   float* __restrict__ gx2, float* __restrict__ gy2,
                                                   float* __restrict__ gar, float* __restrict__ gsc,
                                                   unsigned char* __restrict__ glv,
                                                   int* __restrict__ gV) {
    int b = blockIdx.x;
    int tid = threadIdx.x;
    const int nth = 1024;
    __shared__ u64 key[NSORT];
    __shared__ int sV;

    if (tid == 0) sV = K_TOTAL;
    size_t base = (size_t)b * NSORT;
    for (int i = tid; i < NSORT; i += nth) key[i] = skey[base + i];
    __syncthreads();

    for (int k = 1024; k <= NSORT; k <<= 1) {
        for (int j = k >> 1; j > 0; j >>= 1) {
            for (int i = tid; i < NSORT; i += nth) {
                int p = i ^ j;
                if (p > i) {
                    u64 a = key[i], c = key[p];
                    bool up = (i & k) == 0;
                    if (up ? (a < c) : (a > c)) { key[i] = c; key[p] = a; }
                }
            }
            __syncthreads();
        }
    }

    #pragma unroll
    for (int e = 0; e < 4; ++e) {
        int i = tid * 4 + e;
        u64 kv = key[i];
        int slot = (int)(kv & 0xFFFull);
        float x1 = sx1[base + slot], y1 = sy1[base + slot];
        float x2 = sx2[base + slot], y2 = sy2[base + slot];
        gx1[base + i] = x1; gy1[base + i] = y1;
        gx2[base + i] = x2; gy2[base + i] = y2;
        gar[base + i] = (x2 - x1) * (y2 - y1);
        gsc[base + i] = unsortable((unsigned)(kv >> 32));
        glv[base + i] = slv[base + slot];
        if (i < K_TOTAL && (unsigned)(kv >> 32) < 0x80000000u) atomicMin(&sV, i);
    }
    __syncthreads();
    if (tid == 0) gV[b] = sV;
}

// K3: build triangular suppression bit-matrix, 2D triangle tiling, row+word ranged.
// Also ORs per-row nonzero into rowflag[b][64]. Gate lets later launches exit.
__global__ __launch_bounds__(512) void build_mat(const float* __restrict__ gx1,
                                                 const float* __restrict__ gy1,
                                                 const float* __restrict__ gx2,
                                                 const float* __restrict__ gy2,
                                                 const float* __restrict__ gar,
                                                 const int* __restrict__ gV,
                                                 u64* __restrict__ mat,
                                                 u64* __restrict__ rowflag,
                                                 int rt_start, int rt_count,
                                                 int wt_start, int wt_count,
                                                 const int* __restrict__ gate) {
    unsigned blk = blockIdx.x;
    int wt = wt_start + (int)(blk % (unsigned)wt_count);
    unsigned t = blk / (unsigned)wt_count;
    int b = (int)(t / (unsigned)rt_count);
    int rt = rt_start + (int)(t % (unsigned)rt_count);
    if (gate && gate[b]) return;
    int V = gV[b];
    int i0 = rt << 5;
    if (i0 >= V) return;
    int wbase = i0 >> 6;
    if (wt * 8 + 7 < wbase) return;    // tile fully below diagonal
    int tid = threadIdx.x, lane = tid & 63, wvi = tid >> 6;
    size_t base = (size_t)b * NSORT;

    __shared__ float rx1[32], ry1[32], rx2[32], ry2[32], rar[32];
    __shared__ u64 tile[32][8];
    __shared__ u64 rowor[32];

    int w = wt * 8 + wvi;              // this wave's word (<= 63)
    int j = (w << 6) + lane;
    float c1 = gx1[base + j], c2 = gy1[base + j];
    float c3 = gx2[base + j], c4 = gy2[base + j], ca = gar[base + j];

    if (tid < 32) {
        rx1[tid] = gx1[base + i0 + tid];
        ry1[tid] = gy1[base + i0 + tid];
        rx2[tid] = gx2[base + i0 + tid];
        ry2[tid] = gy2[base + i0 + tid];
        rar[tid] = gar[base + i0 + tid];
        rowor[tid] = 0ull;
    }
    __syncthreads();

    int rmax = min(32, V - i0);
    for (int r = 0; r < rmax; ++r) {
        int i = i0 + r;
        float ix1 = rx1[r], iy1 = ry1[r], ix2 = rx2[r], iy2 = ry2[r], ia = rar[r];
        float lx = fmaxf(ix1, c1);
        float ly = fmaxf(iy1, c2);
        float rx = fminf(ix2, c3);
        float ry = fminf(iy2, c4);
        float wx = fmaxf(rx - lx, 0.f), wy = fmaxf(ry - ly, 0.f);
        float inter = wx * wy;
        float iou = inter / (ia + ca - inter + 1e-9f);
        u64 bits = __ballot(iou > 0.7f && j > i);
        if (lane == 0) tile[r][wvi] = bits;
    }
    __syncthreads();

    // store 32 rows x 8 words (rows < rmax only); accumulate row-nonzero flags.
    if (tid < 256) {
        int r = tid >> 3, ww = tid & 7;
        if (r < rmax) {
            u64 v = tile[r][ww];
            mat[((size_t)b << 18) | ((size_t)(i0 + r) << 6) | (unsigned)(wt * 8 + ww)] = v;
            if (v) atomicOr(&rowor[r], v);
        }
    }
    __syncthreads();
    if (tid < 32 && tid < rmax && rowor[tid] != 0ull) {
        int i = i0 + tid;
        atomicOr(&rowflag[b * 64 + (i >> 6)], 1ull << (i & 63));
    }
}

// K4: phased greedy resolve with rowflag-gated fast paths.
// Phase 1 (gstart=0, glimit=20): only matrix words < 24 are valid; srem words
// >= 20 may absorb garbage but are never read when finishing within 20 groups.
// If not finished, phase 2 RESTARTS from group 0 with the fully-built matrix.
__global__ __launch_bounds__(512) void resolve_emit(const u64* __restrict__ mat,
                                                    const u64* __restrict__ rowflag,
                                                    const float* __restrict__ gx1,
                                                    const float* __restrict__ gy1,
                                                    const float* __restrict__ gx2,
                                                    const float* __restrict__ gy2,
                                                    const float* __restrict__ gsc,
                                                    const unsigned char* __restrict__ glv,
                                                    const int* __restrict__ gV,
                                                    int gstart, int glimit,
                                                    int* __restrict__ st_done,
                                                    int* __restrict__ st_kc,
                                                    u64* __restrict__ st_srem,
                                                    unsigned short* __restrict__ st_klist,
                                                    float* __restrict__ out_boxes,
                                                    float* __restrict__ out_scores) {
    int b = blockIdx.x;
    if (st_done[b]) return;            // earlier phase already emitted
    int tid = threadIdx.x;
    int lane = tid & 63, wvi = tid >> 6;
    __shared__ u64 srem[64];
    __shared__ u64 s_keptg;
    __shared__ int s_kc;
    __shared__ int s_done;
    int V = gV[b];
    int ngroups = (V + 63) >> 6;
    int gend = (glimit < ngroups) ? glimit : ngroups;
    const u64* M = mat + ((size_t)b << 18);
    unsigned short* kl = st_klist + (size_t)b * POST_N;

    if (tid < 64) srem[tid] = (gstart > 0) ? st_srem[b * 64 + tid] : 0ull;
    if (tid == 0) {
        s_kc = (gstart > 0) ? st_kc[b] : 0;
        s_done = (ngroups == 0) ? 1 : 0;
    }
    __syncthreads();

    for (int g = gstart; g < gend; ++g) {
        if (wvi == 0) {
            u64 gw = srem[g];
            int rem = V - (g << 6);
            u64 inmask = (rem >= 64) ? ~0ull : ((1ull << rem) - 1ull);
            u64 alive = ~gw & inmask;
            u64 gf = rowflag[b * 64 + g];
            u64 rw = 0ull;
            if ((alive & gf) != 0ull)
                rw = M[((size_t)((g << 6) + lane) << 6) + (unsigned)g];
            int kc0 = s_kc;
            int kc = kc0;
            u64 keptg = 0;
            bool me = ((alive >> lane) & 1ull) && ((rw & alive) != 0ull);
            if (__ballot(me) == 0ull) {
                // fast path: no in-group suppression possible -> keep all alive
                keptg = alive;
                if ((keptg >> lane) & 1ull) {
                    u64 lowmask = (1ull << lane) - 1ull;
                    int pos = kc0 + __popcll(keptg & lowmask);
                    if (pos < POST_N) kl[pos] = (unsigned short)((g << 6) + lane);
                }
                kc = kc0 + __popcll(keptg);
            } else {
                // exact greedy chain over alive rows
                u64 m = alive;
                while (m) {
                    int k = __ffsll((long long)m) - 1;
                    keptg |= 1ull << k;
                    if (lane == 0 && kc < POST_N) kl[kc] = (unsigned short)((g << 6) + k);
                    kc++;
                    if (kc >= POST_N) break;
                    u64 rk = __shfl(rw, k, 64);
                    m &= ~rk;
                    m &= ~(1ull << k);
                }
            }
            if (lane == 0) {
                s_kc = (kc > POST_N) ? POST_N : kc;
                s_keptg = keptg;
                if (kc >= POST_N || g + 1 >= ngroups) s_done = 1;
            }
        }
        __syncthreads();
        if (s_done) break;
        // cross-group suppression: only kept rows with nonzero rows (flagged)
        u64 keptg = s_keptg & rowflag[b * 64 + g];
        u64 acc = 0;
        int idx = 0;
        u64 m2 = keptg;
        while (m2) {
            int k = __ffsll((long long)m2) - 1; m2 &= m2 - 1;
            if ((idx & 7) == wvi) {
                u64 v = M[((size_t)((g << 6) + k) << 6) + (unsigned)lane];
                if (lane >= g) acc |= v;   // words < g may be stale (already-consumed groups)
            }
            idx++;
        }
        if (acc) atomicOr(&srem[lane], acc);
        __syncthreads();
    }
    __syncthreads();

    if (!s_done) {
        // boundary exit: phase 2 restarts from group 0 (no state needed)
        return;
    }

    int kcf = s_kc;
    if (tid == 0) st_done[b] = 1;

    float* ob = out_boxes + (size_t)b * POST_N * 4;
    float* os = out_scores + (size_t)b * POST_N;
    for (int q = tid; q < POST_N; q += 512) {
        ob[4 * q + 0] = 0.f; ob[4 * q + 1] = 0.f;
        ob[4 * q + 2] = 0.f; ob[4 * q + 3] = 0.f;
        os[q] = 0.f;
    }
    __syncthreads();
    size_t base = (size_t)b * NSORT;
    for (int p = tid; p < kcf; p += 512) {
        int i = kl[p];
        float lo = (float)glv[base + i] * 1025.0f;
        ob[4 * p + 0] = gx1[base + i] - lo;
        ob[4 * p + 1] = gy1[base + i] - lo;
        ob[4 * p + 2] = gx2[base + i] - lo;
        ob[4 * p + 3] = gy2[base + i] - lo;
        os[p] = gsc[base + i];
    }
}

extern "C" void kernel_launch(void* const* d_in, const int* in_sizes, int n_in,
                              void* d_out, int out_size, void* d_ws, size_t ws_size,
                              hipStream_t stream) {
    const float* obj     = (const float*)d_in[0];
    const float* deltas  = (const float*)d_in[1];
    const float* anchors = (const float*)d_in[2];
    float* out_boxes  = (float*)d_out;
    float* out_scores = (float*)d_out + B_BATCH * POST_N * 4;
    char* ws = (char*)d_ws;

    const size_t O_SEL   = 0;        // int[8][4000]           = 128000
    const size_t O_GCNT  = 128000;   // u32[32]
    const size_t O_GEQ   = 128128;   // u32[32]
    const size_t O_T1    = 128256;   // u32[32]  (ends 128384 < 131072)
    const size_t O_HIST  = 131072;   // u32[32][2048]          = 262144
    const size_t O_BX1   = 393216;   // f32[8][4096] each ↓    = 131072
    const size_t O_BY1   = 524288;
    const size_t O_BX2   = 655360;
    const size_t O_BY2   = 786432;
    const size_t O_BAR   = 917504;
    const size_t O_BSC   = 1048576;
    const size_t O_BLV   = 1179648;  // u8[8][4096]            = 32768
    const size_t O_BV    = 1212416;  // int[8]
    const size_t O_DONE  = 1212544;  // int[8]
    const size_t O_KC    = 1212608;  // int[8]
    const size_t O_SREM  = 1212672;  // u64[8][64]             = 4096
    const size_t O_KLIST = 1216768;  // u16[8][1000]           = 16000
    const size_t O_FLAG  = 1232768;  // u64[8][64]             = 4096
    // sort scratch in the hole before O_MAT (no aliasing with mat).
    // gcand (u64[32][3072] = 786432) reuses S_KEY..S_SY2: read by topk_fin
    // BEFORE decode_seg overwrites it (stream-ordered).
    const size_t S_KEY   = 1236864;  // u64[8][4096]           = 262144
    const size_t S_SX1   = 1499008;  // f32[8][4096] each ↓    = 131072
    const size_t S_SY1   = 1630080;
    const size_t S_SX2   = 1761152;
    const size_t S_SY2   = 1892224;
    const size_t S_SLV   = 2023296;  // u8[8][4096]            = 32768 (ends 2056064)
    const size_t O_CAND  = S_KEY;    // u64[32][3072]          = 786432 (ends 2023296)
    const size_t O_MAT   = 2097152;  // u64[8][4096][64]       = 16777216

    const int RT_SPLIT = 40;         // rows < 1280 built eagerly
    const int WT_SPLIT = 3;          // words < 24 built eagerly (covers groups < 20)

    hipMemsetAsync(ws + O_HIST, 0, 262144, stream);
    hipMemsetAsync(ws + O_GCNT, 0, 256, stream);
    hipMemsetAsync(ws + O_DONE, 0, (O_FLAG + 4096) - O_DONE, stream);
    topk_hist<<<512, 512, 0, stream>>>(obj, (unsigned*)(ws + O_HIST));
    topk_thresh<<<32, 512, 0, stream>>>((const unsigned*)(ws + O_HIST),
                                        (unsigned*)(ws + O_T1));
    topk_scan<<<512, 512, 0, stream>>>(obj, (const unsigned*)(ws + O_T1),
                                       (int*)(ws + O_SEL),
                                       (unsigned*)(ws + O_GCNT),
                                       (unsigned*)(ws + O_GEQ),
                                       (u64*)(ws + O_CAND));
    topk_fin<<<32, 512, 0, stream>>>((const unsigned*)(ws + O_HIST),
                                     (const unsigned*)(ws + O_GEQ),
                                     (const u64*)(ws + O_CAND),
                                     (int*)(ws + O_SEL));
    decode_seg<<<64, 512, 0, stream>>>(obj, deltas, anchors, (const int*)(ws + O_SEL),
                                       (u64*)(ws + S_KEY),
                                       (float*)(ws + S_SX1), (float*)(ws + S_SY1),
                                       (float*)(ws + S_SX2), (float*)(ws + S_SY2),
                                       (unsigned char*)(ws + S_SLV));
    merge_sort<<<8, 1024, 0, stream>>>((const u64*)(ws + S_KEY),
                                       (const float*)(ws + S_SX1), (const float*)(ws + S_SY1),
                                       (const float*)(ws + S_SX2), (const float*)(ws + S_SY2),
                                       (const unsigned char*)(ws + S_SLV),
                                       (float*)(ws + O_BX1), (float*)(ws + O_BY1),
                                       (float*)(ws + O_BX2), (float*)(ws + O_BY2),
                                       (float*)(ws + O_BAR), (float*)(ws + O_BSC),
                                       (unsigned char*)(ws + O_BLV), (int*)(ws + O_BV));
    // phase 1: rows < 1280, words < 24 only
    build_mat<<<B_BATCH * RT_SPLIT * WT_SPLIT, 512, 0, stream>>>(
        (const float*)(ws + O_BX1), (const float*)(ws + O_BY1),
        (const float*)(ws + O_BX2), (const float*)(ws + O_BY2),
        (const float*)(ws + O_BAR), (const int*)(ws + O_BV),
        (u64*)(ws + O_MAT), (u64*)(ws + O_FLAG),
        0, RT_SPLIT, 0, WT_SPLIT, (const int*)0);
    resolve_emit<<<8, 512, 0, stream>>>(
        (const u64*)(ws + O_MAT), (const u64*)(ws + O_FLAG),
        (const float*)(ws + O_BX1), (const float*)(ws + O_BY1),
        (const float*)(ws + O_BX2), (const float*)(ws + O_BY2),
        (const float*)(ws + O_BSC), (const unsigned char*)(ws + O_BLV),
        (const int*)(ws + O_BV), 0, RT_SPLIT / 2,
        (int*)(ws + O_DONE), (int*)(ws + O_KC),
        (u64*)(ws + O_SREM), (unsigned short*)(ws + O_KLIST),
        out_boxes, out_scores);
    // phase 2 (all gated; exit immediately when phase 1 finished)
    build_mat<<<B_BATCH * (128 - RT_SPLIT) * 8, 512, 0, stream>>>(
        (const float*)(ws + O_BX1), (const float*)(ws + O_BY1),
        (const float*)(ws + O_BX2), (const float*)(ws + O_BY2),
        (const float*)(ws + O_BAR), (const int*)(ws + O_BV),
        (u64*)(ws + O_MAT), (u64*)(ws + O_FLAG),
        RT_SPLIT, 128 - RT_SPLIT, 0, 8, (const int*)(ws + O_DONE));
    build_mat<<<B_BATCH * RT_SPLIT * (8 - WT_SPLIT), 512, 0, stream>>>(
        (const float*)(ws + O_BX1), (const float*)(ws + O_BY1),
        (const float*)(ws + O_BX2), (const float*)(ws + O_BY2),
        (const float*)(ws + O_BAR), (const int*)(ws + O_BV),
        (u64*)(ws + O_MAT), (u64*)(ws + O_FLAG),
        0, RT_SPLIT, WT_SPLIT, 8 - WT_SPLIT, (const int*)(ws + O_DONE));
    resolve_emit<<<8, 512, 0, stream>>>(
        (const u64*)(ws + O_MAT), (const u64*)(ws + O_FLAG),
        (const float*)(ws + O_BX1), (const float*)(ws + O_BY1),
        (const float*)(ws + O_BX2), (const float*)(ws + O_BY2),
        (const float*)(ws + O_BSC), (const unsigned char*)(ws + O_BLV),
        (const int*)(ws + O_BV), 0, 64,
        (int*)(ws + O_DONE), (int*)(ws + O_KC),
        (u64*)(ws + O_SREM), (unsigned short*)(ws + O_KLIST),
        out_boxes, out_scores);
}

// Round 23
// 138.005 us; speedup vs baseline: 1.6342x; 1.6342x over previous
//
#include <hip/hip_runtime.h>
#include <math.h>

#define A_TOTAL 261120
#define B_BATCH 8
#define K_PER_LVL 1000
#define K_TOTAL 4000
#define NSORT 4096
#define POST_N 1000
#define NEGV -1e30f
#define BBOX_CLIP 4.135166556742356f
#define CAND_CAP 3072

typedef unsigned long long u64;

__device__ __forceinline__ unsigned sortable(float f) {
    unsigned u = __float_as_uint(f);
    return (u & 0x80000000u) ? ~u : (u | 0x80000000u);
}

__device__ __forceinline__ float unsortable(unsigned u) {
    return (u & 0x80000000u) ? __uint_as_float(u & 0x7FFFFFFFu) : __uint_as_float(~u);
}

// Parallel "find threshold bin from top" over hist[NB]; all 512 threads call.
// Result: s_res[0]=T (bin), s_res[1]=G (count strictly above bin T).
template<int NB>
__device__ __forceinline__ void radix_sel(unsigned* hist, unsigned need,
                                          unsigned* s_res, unsigned* swsum) {
    const int per = NB >> 9;
    int tid = threadIdx.x;
    unsigned vals[per];
    unsigned part = 0;
    #pragma unroll
    for (int e = 0; e < per; ++e) {
        unsigned v = hist[NB - 1 - (tid * per + e)];   // high bins first
        vals[e] = v; part += v;
    }
    int lane = tid & 63, wv = tid >> 6;
    unsigned x = part;
    #pragma unroll
    for (int d = 1; d < 64; d <<= 1) {
        unsigned y = __shfl_up(x, d);
        if (lane >= d) x += y;
    }
    if (lane == 63) swsum[wv] = x;
    __syncthreads();
    unsigned woff = 0;
    for (int w = 0; w < wv; ++w) woff += swsum[w];
    unsigned run = woff + x - part;    // exclusive prefix (count in bins above)
    #pragma unroll
    for (int e = 0; e < per; ++e) {
        unsigned c = vals[e];
        if (run < need && run + c >= need) {
            s_res[0] = (unsigned)(NB - 1 - (tid * per + e));
            s_res[1] = run;
        }
        run += c;
    }
    __syncthreads();
}

// ============ FAST PATH ============

// K1a: 512 blocks (b*64 + chunk). Per-chunk LDS hist -> global hist[b][lvl].
__global__ __launch_bounds__(512) void topk_hist(const float* __restrict__ obj,
                                                 unsigned* __restrict__ hist) {
    int blk = blockIdx.x;
    int b = blk >> 6, c = blk & 63;
    int lvl = c < 48 ? 0 : c < 60 ? 1 : c < 63 ? 2 : 3;
    const float4* src = (const float4*)(obj + (size_t)b * A_TOTAL + (size_t)c * 4096);
    int n4c = (c == 63) ? 768 : 1024;
    __shared__ unsigned h[2048];
    int tid = threadIdx.x;
    for (int i = tid; i < 2048; i += 512) h[i] = 0;
    __syncthreads();
    for (int i4 = tid; i4 < n4c; i4 += 512) {
        float4 v = src[i4];
        atomicAdd(&h[sortable(v.x) >> 21], 1u);
        atomicAdd(&h[sortable(v.y) >> 21], 1u);
        atomicAdd(&h[sortable(v.z) >> 21], 1u);
        atomicAdd(&h[sortable(v.w) >> 21], 1u);
    }
    __syncthreads();
    unsigned* gh = hist + ((size_t)(b * 4 + lvl) << 11);
    for (int i = tid; i < 2048; i += 512) {
        unsigned cc = h[i];
        if (cc) atomicAdd(&gh[i], cc);
    }
}

// K1b: 32 blocks (b,lvl). Threshold bin T1 from hist.
__global__ __launch_bounds__(512) void topk_thresh(const unsigned* __restrict__ hist,
                                                   unsigned* __restrict__ t1arr) {
    __shared__ unsigned h[2048];
    __shared__ unsigned s_res[2];
    __shared__ unsigned swsum[8];
    int tid = threadIdx.x;
    for (int i = tid; i < 2048; i += 512) h[i] = hist[((size_t)blockIdx.x << 11) + i];
    __syncthreads();
    radix_sel<2048>(h, K_PER_LVL, s_res, swsum);
    if (tid == 0) t1arr[blockIdx.x] = s_res[0];
}

// K1c: 512 blocks. Two-phase scan: count + block prefix + ONE atomic per block
// per counter, then register-cached writes at reserved offsets. Order within
// sel is irrelevant (final sort ties break by unique anchor index).
__global__ __launch_bounds__(512) void topk_scan(const float* __restrict__ obj,
                                                 const unsigned* __restrict__ t1arr,
                                                 int* __restrict__ sel,
                                                 unsigned* __restrict__ gcnt,
                                                 unsigned* __restrict__ geq,
                                                 u64* __restrict__ gcand) {
    int blk = blockIdx.x;
    int b = blk >> 6, c = blk & 63;
    int lvl = c < 48 ? 0 : c < 60 ? 1 : c < 63 ? 2 : 3;
    const int offs[4] = {0, 196608, 245760, 258048};
    int off = offs[lvl];
    const float4* src = (const float4*)(obj + (size_t)b * A_TOTAL + (size_t)c * 4096);
    int n4c = (c == 63) ? 768 : 1024;
    int bl = b * 4 + lvl;
    unsigned T1 = t1arr[bl];
    int* out = sel + (size_t)bl * K_PER_LVL;
    u64* cand = gcand + (size_t)bl * CAND_CAP;
    int tid = threadIdx.x;
    int lane = tid & 63, wv = tid >> 6;
    int lbase = c * 4096 - off;          // chunk start, level-local
    __shared__ unsigned swsum1[8], swsum2[8];
    __shared__ unsigned s_base1, s_base2;

    // load (<=2 float4 per thread), keep in registers
    float4 va = src[tid];
    bool have2 = (tid + 512) < n4c;
    float4 vb = have2 ? src[tid + 512] : va;

    unsigned ka[4], kb[4];
    ka[0] = sortable(va.x); ka[1] = sortable(va.y);
    ka[2] = sortable(va.z); ka[3] = sortable(va.w);
    kb[0] = sortable(vb.x); kb[1] = sortable(vb.y);
    kb[2] = sortable(vb.z); kb[3] = sortable(vb.w);

    unsigned c1 = 0, c2 = 0;
    #pragma unroll
    for (int e = 0; e < 4; ++e) {
        unsigned bin = ka[e] >> 21;
        c1 += (bin > T1) ? 1u : 0u;
        c2 += (bin == T1) ? 1u : 0u;
    }
    if (have2) {
        #pragma unroll
        for (int e = 0; e < 4; ++e) {
            unsigned bin = kb[e] >> 21;
            c1 += (bin > T1) ? 1u : 0u;
            c2 += (bin == T1) ? 1u : 0u;
        }
    }

    // block exclusive prefix for c1 and c2
    unsigned x1 = c1, x2 = c2;
    #pragma unroll
    for (int d = 1; d < 64; d <<= 1) {
        unsigned y1 = __shfl_up(x1, d);
        unsigned y2 = __shfl_up(x2, d);
        if (lane >= d) { x1 += y1; x2 += y2; }
    }
    if (lane == 63) { swsum1[wv] = x1; swsum2[wv] = x2; }
    __syncthreads();
    unsigned woff1 = 0, woff2 = 0;
    for (int w = 0; w < wv; ++w) { woff1 += swsum1[w]; woff2 += swsum2[w]; }
    unsigned ex1 = woff1 + x1 - c1;
    unsigned ex2 = woff2 + x2 - c2;
    if (tid == 0) {
        unsigned t1t = 0, t2t = 0;
        for (int w = 0; w < 8; ++w) { t1t += swsum1[w]; t2t += swsum2[w]; }
        s_base1 = t1t ? atomicAdd(&gcnt[bl], t1t) : 0u;
        s_base2 = t2t ? atomicAdd(&geq[bl], t2t) : 0u;
    }
    __syncthreads();
    unsigned p1 = s_base1 + ex1;
    unsigned p2 = s_base2 + ex2;

    #pragma unroll
    for (int e = 0; e < 4; ++e) {
        unsigned k = ka[e];
        unsigned bin = k >> 21;
        int i = lbase + 4 * tid + e;
        if (bin > T1) { out[p1++] = off + i; }
        else if (bin == T1) {
            if (p2 < CAND_CAP)
                cand[p2] = (((u64)(k & 0x1FFFFFu)) << 18)
                         | (u64)(0x3FFFFu - (unsigned)i);
            p2++;
        }
    }
    if (have2) {
        #pragma unroll
        for (int e = 0; e < 4; ++e) {
            unsigned k = kb[e];
            unsigned bin = k >> 21;
            int i = lbase + 4 * (tid + 512) + e;
            if (bin > T1) { out[p1++] = off + i; }
            else if (bin == T1) {
                if (p2 < CAND_CAP)
                    cand[p2] = (((u64)(k & 0x1FFFFFu)) << 18)
                             | (u64)(0x3FFFFu - (unsigned)i);
                p2++;
            }
        }
    }
}

// K1d: 32 blocks. Exact top-m of boundary-bin candidates via 3x13-bit radix
// select on 39-bit unique keys; append at out[G1..].
__global__ __launch_bounds__(512) void topk_fin(const unsigned* __restrict__ hist,
                                                const unsigned* __restrict__ geq,
                                                const u64* __restrict__ gcand,
                                                int* __restrict__ sel) {
    int bl = blockIdx.x;
    const int offs[4] = {0, 196608, 245760, 258048};
    int off = offs[bl & 3];
    __shared__ unsigned h[8192];
    __shared__ u64 cand[CAND_CAP];
    __shared__ unsigned s_res[2];
    __shared__ unsigned swsum[8];
    __shared__ unsigned s_c2;
    int tid = threadIdx.x;

    for (int i = tid; i < 2048; i += 512) h[i] = hist[((size_t)bl << 11) + i];
    if (tid == 0) s_c2 = 0;
    __syncthreads();
    radix_sel<2048>(h, K_PER_LVL, s_res, swsum);
    unsigned G1 = s_res[1];
    int E = (int)min(geq[bl], (unsigned)CAND_CAP);
    const u64* gc = gcand + (size_t)bl * CAND_CAP;
    for (int e = tid; e < E; e += 512) cand[e] = gc[e];
    __syncthreads();
    unsigned m = K_PER_LVL - G1;

    // pass A: bits 38:26
    for (int i = tid; i < 8192; i += 512) h[i] = 0;
    __syncthreads();
    for (int e = tid; e < E; e += 512) atomicAdd(&h[(unsigned)(cand[e] >> 26)], 1u);
    __syncthreads();
    radix_sel<8192>(h, m, s_res, swsum);
    unsigned TA = s_res[0], GA = s_res[1];
    // pass B: bits 25:13 among prefix TA
    for (int i = tid; i < 8192; i += 512) h[i] = 0;
    __syncthreads();
    for (int e = tid; e < E; e += 512) {
        u64 ck = cand[e];
        if ((unsigned)(ck >> 26) == TA) atomicAdd(&h[(unsigned)(ck >> 13) & 0x1FFFu], 1u);
    }
    __syncthreads();
    radix_sel<8192>(h, m - GA, s_res, swsum);
    unsigned TB = s_res[0], GB = s_res[1];
    // pass C: bits 12:0 among prefix (TA,TB)
    for (int i = tid; i < 8192; i += 512) h[i] = 0;
    __syncthreads();
    unsigned pref26 = (TA << 13) | TB;
    for (int e = tid; e < E; e += 512) {
        u64 ck = cand[e];
        if ((unsigned)(ck >> 13) == pref26) atomicAdd(&h[(unsigned)ck & 0x1FFFu], 1u);
    }
    __syncthreads();
    radix_sel<8192>(h, m - GA - GB, s_res, swsum);
    unsigned TC = s_res[0];
    u64 KSTAR = (((u64)TA) << 26) | (((u64)TB) << 13) | (u64)TC;
    int* out = sel + (size_t)bl * K_PER_LVL;
    for (int e = tid; e < E; e += 512) {
        u64 ck = cand[e];
        if (ck >= KSTAR) {
            unsigned p = atomicAdd(&s_c2, 1u);
            out[G1 + p] = off + (int)(0x3FFFFu - (unsigned)(ck & 0x3FFFFu));
        }
    }
}

// K2a: decode slot SoA to scratch + sort own 512-key segment in LDS
// (bitonic stages k=2..512; all pairs intra-segment; global-index direction).
// Grid 64: blockIdx = b*8 + seg.
__global__ __launch_bounds__(512) void decode_seg(const float* __restrict__ obj,
                                                  const float* __restrict__ deltas,
                                                  const float* __restrict__ anchors,
                                                  const int* __restrict__ sel,
                                                  u64* __restrict__ skey,
                                                  float* __restrict__ sx1, float* __restrict__ sy1,
                                                  float* __restrict__ sx2, float* __restrict__ sy2,
                                                  unsigned char* __restrict__ slv) {
    int b = blockIdx.x >> 3, seg = blockIdx.x & 7;
    int tid = threadIdx.x;
    __shared__ u64 kk[512];
    int s = (seg << 9) + tid;
    size_t base = (size_t)b * NSORT + s;

    if (s < K_TOTAL) {
        int g = sel[(size_t)b * K_TOTAL + s];
        float score = obj[(size_t)b * A_TOTAL + g];
        float4 dl = *(const float4*)(deltas + ((size_t)b * A_TOTAL + g) * 4);
        float4 an = *(const float4*)(anchors + (size_t)g * 4);
        float wa = an.z - an.x, ha = an.w - an.y;
        float cxa = an.x + 0.5f * wa, cya = an.y + 0.5f * ha;
        float dw = fminf(dl.z, BBOX_CLIP), dh = fminf(dl.w, BBOX_CLIP);
        float cx = dl.x * wa + cxa, cy = dl.y * ha + cya;
        float w = expf(dw) * wa, h = expf(dh) * ha;
        float x1 = cx - 0.5f * w, y1 = cy - 0.5f * h;
        float x2 = cx + 0.5f * w, y2 = cy + 0.5f * h;
        x1 = fminf(fmaxf(x1, 0.f), 1024.f);
        y1 = fminf(fmaxf(y1, 0.f), 1024.f);
        x2 = fminf(fmaxf(x2, 0.f), 1024.f);
        y2 = fminf(fmaxf(y2, 0.f), 1024.f);
        bool valid = (x2 - x1 >= 0.001f) && (y2 - y1 >= 0.001f) && (score >= 0.f);
        float sm = valid ? score : NEGV;
        int lv = (g >= 258048) ? 3 : (g >= 245760) ? 2 : (g >= 196608) ? 1 : 0;
        float lo = (float)lv * 1025.0f;
        sx1[base] = x1 + lo; sy1[base] = y1 + lo;
        sx2[base] = x2 + lo; sy2[base] = y2 + lo;
        slv[base] = (unsigned char)lv;
        kk[tid] = ((u64)sortable(sm) << 32)
                | ((u64)(0x3FFFFu - (unsigned)g) << 12)
                | (unsigned)s;
    } else {
        sx1[base] = 0.f; sy1[base] = 0.f; sx2[base] = 0.f; sy2[base] = 0.f;
        slv[base] = 0;
        kk[tid] = ((u64)sortable(NEGV) << 32) | (unsigned)s;
    }
    __syncthreads();

    for (int k = 2; k <= 512; k <<= 1) {
        for (int j = k >> 1; j > 0; j >>= 1) {
            int p = tid ^ j;
            if (p > tid) {
                u64 a = kk[tid], c = kk[p];
                bool up = (s & k) == 0;        // global-index direction
                if (up ? (a < c) : (a > c)) { kk[tid] = c; kk[p] = a; }
            }
            __syncthreads();
        }
    }
    skey[base] = kk[tid];
}

// K2b: merge sorted 512-segments (bitonic stages k=1024..4096, keys-only LDS),
// then gather slot SoA from scratch and emit sorted SoA + V. Grid 8.
__global__ __launch_bounds__(1024) void merge_sort(const u64* __restrict__ skey,
                                                   const float* __restrict__ sx1,
                                                   const float* __restrict__ sy1,
                                                   const float* __restrict__ sx2,
                                                   const float* __restrict__ sy2,
                                                   const unsigned char* __restrict__ slv,
                                                   float* __restrict__ gx1, float* __restrict__ gy1,
                                                   float* __restrict__ gx2, float* __restrict__ gy2,
                                                   float* __restrict__ gar, float* __restrict__ gsc,
                                                   unsigned char* __restrict__ glv,
                                                   int* __restrict__ gV) {
    int b = blockIdx.x;
    int tid = threadIdx.x;
    const int nth = 1024;
    __shared__ u64 key[NSORT];
    __shared__ int sV;

    if (tid == 0) sV = K_TOTAL;
    size_t base = (size_t)b * NSORT;
    for (int i = tid; i < NSORT; i += nth) key[i] = skey[base + i];
    __syncthreads();

    for (int k = 1024; k <= NSORT; k <<= 1) {
        for (int j = k >> 1; j > 0; j >>= 1) {
            for (int i = tid; i < NSORT; i += nth) {
                int p = i ^ j;
                if (p > i) {
                    u64 a = key[i], c = key[p];
                    bool up = (i & k) == 0;
                    if (up ? (a < c) : (a > c)) { key[i] = c; key[p] = a; }
                }
            }
            __syncthreads();
        }
    }

    #pragma unroll
    for (int e = 0; e < 4; ++e) {
        int i = tid * 4 + e;
        u64 kv = key[i];
        int slot = (int)(kv & 0xFFFull);
        float x1 = sx1[base + slot], y1 = sy1[base + slot];
        float x2 = sx2[base + slot], y2 = sy2[base + slot];
        gx1[base + i] = x1; gy1[base + i] = y1;
        gx2[base + i] = x2; gy2[base + i] = y2;
        gar[base + i] = (x2 - x1) * (y2 - y1);
        gsc[base + i] = unsortable((unsigned)(kv >> 32));
        glv[base + i] = slv[base + slot];
        if (i < K_TOTAL && (unsigned)(kv >> 32) < 0x80000000u) atomicMin(&sV, i);
    }
    __syncthreads();
    if (tid == 0) gV[b] = sV;
}

// K3: build triangular suppression bit-matrix, 2D triangle tiling, row+word ranged.
// Also ORs per-row nonzero into rowflag[b][64]. Gate lets later launches exit.
__global__ __launch_bounds__(512) void build_mat(const float* __restrict__ gx1,
                                                 const float* __restrict__ gy1,
                                                 const float* __restrict__ gx2,
                                                 const float* __restrict__ gy2,
                                                 const float* __restrict__ gar,
                                                 const int* __restrict__ gV,
                                                 u64* __restrict__ mat,
                                                 u64* __restrict__ rowflag,
                                                 int rt_start, int rt_count,
                                                 int wt_start, int wt_count,
                                                 const int* __restrict__ gate) {
    unsigned blk = blockIdx.x;
    int wt = wt_start + (int)(blk % (unsigned)wt_count);
    unsigned t = blk / (unsigned)wt_count;
    int b = (int)(t / (unsigned)rt_count);
    int rt = rt_start + (int)(t % (unsigned)rt_count);
    if (gate && gate[b]) return;
    int V = gV[b];
    int i0 = rt << 5;
    if (i0 >= V) return;
    int wbase = i0 >> 6;
    if (wt * 8 + 7 < wbase) return;    // tile fully below diagonal
    int tid = threadIdx.x, lane = tid & 63, wvi = tid >> 6;
    size_t base = (size_t)b * NSORT;

    __shared__ float rx1[32], ry1[32], rx2[32], ry2[32], rar[32];
    __shared__ u64 tile[32][8];
    __shared__ u64 rowor[32];

    int w = wt * 8 + wvi;              // this wave's word (<= 63)
    int j = (w << 6) + lane;
    float c1 = gx1[base + j], c2 = gy1[base + j];
    float c3 = gx2[base + j], c4 = gy2[base + j], ca = gar[base + j];

    if (tid < 32) {
        rx1[tid] = gx1[base + i0 + tid];
        ry1[tid] = gy1[base + i0 + tid];
        rx2[tid] = gx2[base + i0 + tid];
        ry2[tid] = gy2[base + i0 + tid];
        rar[tid] = gar[base + i0 + tid];
        rowor[tid] = 0ull;
    }
    __syncthreads();

    int rmax = min(32, V - i0);
    for (int r = 0; r < rmax; ++r) {
        int i = i0 + r;
        float ix1 = rx1[r], iy1 = ry1[r], ix2 = rx2[r], iy2 = ry2[r], ia = rar[r];
        float lx = fmaxf(ix1, c1);
        float ly = fmaxf(iy1, c2);
        float rx = fminf(ix2, c3);
        float ry = fminf(iy2, c4);
        float wx = fmaxf(rx - lx, 0.f), wy = fmaxf(ry - ly, 0.f);
        float inter = wx * wy;
        float iou = inter / (ia + ca - inter + 1e-9f);
        u64 bits = __ballot(iou > 0.7f && j > i);
        if (lane == 0) tile[r][wvi] = bits;
    }
    __syncthreads();

    // store 32 rows x 8 words (rows < rmax only); accumulate row-nonzero flags.
    if (tid < 256) {
        int r = tid >> 3, ww = tid & 7;
        if (r < rmax) {
            u64 v = tile[r][ww];
            mat[((size_t)b << 18) | ((size_t)(i0 + r) << 6) | (unsigned)(wt * 8 + ww)] = v;
            if (v) atomicOr(&rowor[r], v);
        }
    }
    __syncthreads();
    if (tid < 32 && tid < rmax && rowor[tid] != 0ull) {
        int i = i0 + tid;
        atomicOr(&rowflag[b * 64 + (i >> 6)], 1ull << (i & 63));
    }
}

// K4: phased greedy resolve with rowflag-gated fast paths.
// Phase 1 (gstart=0, glimit=20): only matrix words < 24 are valid; srem words
// >= 20 may absorb garbage but are never read when finishing within 20 groups.
// If not finished, phase 2 RESTARTS from group 0 with the fully-built matrix.
__global__ __launch_bounds__(512) void resolve_emit(const u64* __restrict__ mat,
                                                    const u64* __restrict__ rowflag,
                                                    const float* __restrict__ gx1,
                                                    const float* __restrict__ gy1,
                                                    const float* __restrict__ gx2,
                                                    const float* __restrict__ gy2,
                                                    const float* __restrict__ gsc,
                                                    const unsigned char* __restrict__ glv,
                                                    const int* __restrict__ gV,
                                                    int gstart, int glimit,
                                                    int* __restrict__ st_done,
                                                    int* __restrict__ st_kc,
                                                    u64* __restrict__ st_srem,
                                                    unsigned short* __restrict__ st_klist,
                                                    float* __restrict__ out_boxes,
                                                    float* __restrict__ out_scores) {
    int b = blockIdx.x;
    if (st_done[b]) return;            // earlier phase already emitted
    int tid = threadIdx.x;
    int lane = tid & 63, wvi = tid >> 6;
    __shared__ u64 srem[64];
    __shared__ u64 s_keptg;
    __shared__ int s_kc;
    __shared__ int s_done;
    int V = gV[b];
    int ngroups = (V + 63) >> 6;
    int gend = (glimit < ngroups) ? glimit : ngroups;
    const u64* M = mat + ((size_t)b << 18);
    unsigned short* kl = st_klist + (size_t)b * POST_N;

    if (tid < 64) srem[tid] = (gstart > 0) ? st_srem[b * 64 + tid] : 0ull;
    if (tid == 0) {
        s_kc = (gstart > 0) ? st_kc[b] : 0;
        s_done = (ngroups == 0) ? 1 : 0;
    }
    __syncthreads();

    for (int g = gstart; g < gend; ++g) {
        if (wvi == 0) {
            u64 gw = srem[g];
            int rem = V - (g << 6);
            u64 inmask = (rem >= 64) ? ~0ull : ((1ull << rem) - 1ull);
            u64 alive = ~gw & inmask;
            u64 gf = rowflag[b * 64 + g];
            u64 rw = 0ull;
            if ((alive & gf) != 0ull)
                rw = M[((size_t)((g << 6) + lane) << 6) + (unsigned)g];
            int kc0 = s_kc;
            int kc = kc0;
            u64 keptg = 0;
            bool me = ((alive >> lane) & 1ull) && ((rw & alive) != 0ull);
            if (__ballot(me) == 0ull) {
                // fast path: no in-group suppression possible -> keep all alive
                keptg = alive;
                if ((keptg >> lane) & 1ull) {
                    u64 lowmask = (1ull << lane) - 1ull;
                    int pos = kc0 + __popcll(keptg & lowmask);
                    if (pos < POST_N) kl[pos] = (unsigned short)((g << 6) + lane);
                }
                kc = kc0 + __popcll(keptg);
            } else {
                // exact greedy chain over alive rows
                u64 m = alive;
                while (m) {
                    int k = __ffsll((long long)m) - 1;
                    keptg |= 1ull << k;
                    if (lane == 0 && kc < POST_N) kl[kc] = (unsigned short)((g << 6) + k);
                    kc++;
                    if (kc >= POST_N) break;
                    u64 rk = __shfl(rw, k, 64);
                    m &= ~rk;
                    m &= ~(1ull << k);
                }
            }
            if (lane == 0) {
                s_kc = (kc > POST_N) ? POST_N : kc;
                s_keptg = keptg;
                if (kc >= POST_N || g + 1 >= ngroups) s_done = 1;
            }
        }
        __syncthreads();
        if (s_done) break;
        // cross-group suppression: only kept rows with nonzero rows (flagged)
        u64 keptg = s_keptg & rowflag[b * 64 + g];
        u64 acc = 0;
        int idx = 0;
        u64 m2 = keptg;
        while (m2) {
            int k = __ffsll((long long)m2) - 1; m2 &= m2 - 1;
            if ((idx & 7) == wvi) {
                u64 v = M[((size_t)((g << 6) + k) << 6) + (unsigned)lane];
                if (lane >= g) acc |= v;   // words < g may be stale (already-consumed groups)
            }
            idx++;
        }
        if (acc) atomicOr(&srem[lane], acc);
        __syncthreads();
    }
    __syncthreads();

    if (!s_done) {
        // boundary exit: phase 2 restarts from group 0 (no state needed)
        return;
    }

    int kcf = s_kc;
    if (tid == 0) st_done[b] = 1;

    float* ob = out_boxes + (size_t)b * POST_N * 4;
    float* os = out_scores + (size_t)b * POST_N;
    for (int q = tid; q < POST_N; q += 512) {
        ob[4 * q + 0] = 0.f; ob[4 * q + 1] = 0.f;
        ob[4 * q + 2] = 0.f; ob[4 * q + 3] = 0.f;
        os[q] = 0.f;
    }
    __syncthreads();
    size_t base = (size_t)b * NSORT;
    for (int p = tid; p < kcf; p += 512) {
        int i = kl[p];
        float lo = (float)glv[base + i] * 1025.0f;
        ob[4 * p + 0] = gx1[base + i] - lo;
        ob[4 * p + 1] = gy1[base + i] - lo;
        ob[4 * p + 2] = gx2[base + i] - lo;
        ob[4 * p + 3] = gy2[base + i] - lo;
        os[p] = gsc[base + i];
    }
}

extern "C" void kernel_launch(void* const* d_in, const int* in_sizes, int n_in,
                              void* d_out, int out_size, void* d_ws, size_t ws_size,
                              hipStream_t stream) {
    const float* obj     = (const float*)d_in[0];
    const float* deltas  = (const float*)d_in[1];
    const float* anchors = (const float*)d_in[2];
    float* out_boxes  = (float*)d_out;
    float* out_scores = (float*)d_out + B_BATCH * POST_N * 4;
    char* ws = (char*)d_ws;

    const size_t O_SEL   = 0;        // int[8][4000]           = 128000
    const size_t O_GCNT  = 128000;   // u32[32]
    const size_t O_GEQ   = 128128;   // u32[32]
    const size_t O_T1    = 128256;   // u32[32]  (ends 128384 < 131072)
    const size_t O_HIST  = 131072;   // u32[32][2048]          = 262144
    const size_t O_BX1   = 393216;   // f32[8][4096] each ↓    = 131072
    const size_t O_BY1   = 524288;
    const size_t O_BX2   = 655360;
    const size_t O_BY2   = 786432;
    const size_t O_BAR   = 917504;
    const size_t O_BSC   = 1048576;
    const size_t O_BLV   = 1179648;  // u8[8][4096]            = 32768
    const size_t O_BV    = 1212416;  // int[8]
    const size_t O_DONE  = 1212544;  // int[8]
    const size_t O_KC    = 1212608;  // int[8]
    const size_t O_SREM  = 1212672;  // u64[8][64]             = 4096
    const size_t O_KLIST = 1216768;  // u16[8][1000]           = 16000
    const size_t O_FLAG  = 1232768;  // u64[8][64]             = 4096
    // sort scratch in the hole before O_MAT (no aliasing with mat).
    // gcand (u64[32][3072] = 786432) reuses S_KEY..S_SY2: read by topk_fin
    // BEFORE decode_seg overwrites it (stream-ordered).
    const size_t S_KEY   = 1236864;  // u64[8][4096]           = 262144
    const size_t S_SX1   = 1499008;  // f32[8][4096] each ↓    = 131072
    const size_t S_SY1   = 1630080;
    const size_t S_SX2   = 1761152;
    const size_t S_SY2   = 1892224;
    const size_t S_SLV   = 2023296;  // u8[8][4096]            = 32768 (ends 2056064)
    const size_t O_CAND  = S_KEY;    // u64[32][3072]          = 786432 (ends 2023296)
    const size_t O_MAT   = 2097152;  // u64[8][4096][64]       = 16777216

    const int RT_SPLIT = 40;         // rows < 1280 built eagerly
    const int WT_SPLIT = 3;          // words < 24 built eagerly (covers groups < 20)

    hipMemsetAsync(ws + O_HIST, 0, 262144, stream);
    hipMemsetAsync(ws + O_GCNT, 0, 256, stream);
    hipMemsetAsync(ws + O_DONE, 0, (O_FLAG + 4096) - O_DONE, stream);
    topk_hist<<<512, 512, 0, stream>>>(obj, (unsigned*)(ws + O_HIST));
    topk_thresh<<<32, 512, 0, stream>>>((const unsigned*)(ws + O_HIST),
                                        (unsigned*)(ws + O_T1));
    topk_scan<<<512, 512, 0, stream>>>(obj, (const unsigned*)(ws + O_T1),
                                       (int*)(ws + O_SEL),
                                       (unsigned*)(ws + O_GCNT),
                                       (unsigned*)(ws + O_GEQ),
                                       (u64*)(ws + O_CAND));
    topk_fin<<<32, 512, 0, stream>>>((const unsigned*)(ws + O_HIST),
                                     (const unsigned*)(ws + O_GEQ),
                                     (const u64*)(ws + O_CAND),
                                     (int*)(ws + O_SEL));
    decode_seg<<<64, 512, 0, stream>>>(obj, deltas, anchors, (const int*)(ws + O_SEL),
                                       (u64*)(ws + S_KEY),
                                       (float*)(ws + S_SX1), (float*)(ws + S_SY1),
                                       (float*)(ws + S_SX2), (float*)(ws + S_SY2),
                                       (unsigned char*)(ws + S_SLV));
    merge_sort<<<8, 1024, 0, stream>>>((const u64*)(ws + S_KEY),
                                       (const float*)(ws + S_SX1), (const float*)(ws + S_SY1),
                                       (const float*)(ws + S_SX2), (const float*)(ws + S_SY2),
                                       (const unsigned char*)(ws + S_SLV),
                                       (float*)(ws + O_BX1), (float*)(ws + O_BY1),
                                       (float*)(ws + O_BX2), (float*)(ws + O_BY2),
                                       (float*)(ws + O_BAR), (float*)(ws + O_BSC),
                                       (unsigned char*)(ws + O_BLV), (int*)(ws + O_BV));
    // phase 1: rows < 1280, words < 24 only
    build_mat<<<B_BATCH * RT_SPLIT * WT_SPLIT, 512, 0, stream>>>(
        (const float*)(ws + O_BX1), (const float*)(ws + O_BY1),
        (const float*)(ws + O_BX2), (const float*)(ws + O_BY2),
        (const float*)(ws + O_BAR), (const int*)(ws + O_BV),
        (u64*)(ws + O_MAT), (u64*)(ws + O_FLAG),
        0, RT_SPLIT, 0, WT_SPLIT, (const int*)0);
    resolve_emit<<<8, 512, 0, stream>>>(
        (const u64*)(ws + O_MAT), (const u64*)(ws + O_FLAG),
        (const float*)(ws + O_BX1), (const float*)(ws + O_BY1),
        (const float*)(ws + O_BX2), (const float*)(ws + O_BY2),
        (const float*)(ws + O_BSC), (const unsigned char*)(ws + O_BLV),
        (const int*)(ws + O_BV), 0, RT_SPLIT / 2,
        (int*)(ws + O_DONE), (int*)(ws + O_KC),
        (u64*)(ws + O_SREM), (unsigned short*)(ws + O_KLIST),
        out_boxes, out_scores);
    // phase 2 (all gated; exit immediately when phase 1 finished)
    build_mat<<<B_BATCH * (128 - RT_SPLIT) * 8, 512, 0, stream>>>(
        (const float*)(ws + O_BX1), (const float*)(ws + O_BY1),
        (const float*)(ws + O_BX2), (const float*)(ws + O_BY2),
        (const float*)(ws + O_BAR), (const int*)(ws + O_BV),
        (u64*)(ws + O_MAT), (u64*)(ws + O_FLAG),
        RT_SPLIT, 128 - RT_SPLIT, 0, 8, (const int*)(ws + O_DONE));
    build_mat<<<B_BATCH * RT_SPLIT * (8 - WT_SPLIT), 512, 0, stream>>>(
        (const float*)(ws + O_BX1), (const float*)(ws + O_BY1),
        (const float*)(ws + O_BX2), (const float*)(ws + O_BY2),
        (const float*)(ws + O_BAR), (const int*)(ws + O_BV),
        (u64*)(ws + O_MAT), (u64*)(ws + O_FLAG),
        0, RT_SPLIT, WT_SPLIT, 8 - WT_SPLIT, (const int*)(ws + O_DONE));
    resolve_emit<<<8, 512, 0, stream>>>(
        (const u64*)(ws + O_MAT), (const u64*)(ws + O_FLAG),
        (const float*)(ws + O_BX1), (const float*)(ws + O_BY1),
        (const float*)(ws + O_BX2), (const float*)(ws + O_BY2),
        (const float*)(ws + O_BSC), (const unsigned char*)(ws + O_BLV),
        (const int*)(ws + O_BV), 0, 64,
        (int*)(ws + O_DONE), (int*)(ws + O_KC),
        (u64*)(ws + O_SREM), (unsigned short*)(ws + O_KLIST),
        out_boxes, out_scores);
}

// Round 24
// 126.285 us; speedup vs baseline: 1.7858x; 1.0928x over previous
//
#include <hip/hip_runtime.h>
#include <math.h>

#define A_TOTAL 261120
#define B_BATCH 8
#define K_PER_LVL 1000
#define K_TOTAL 4000
#define NSORT 4096
#define POST_N 1000
#define NEGV -1e30f
#define BBOX_CLIP 4.135166556742356f
#define CAND_CAP 3072

typedef unsigned long long u64;

__device__ __forceinline__ unsigned sortable(float f) {
    unsigned u = __float_as_uint(f);
    return (u & 0x80000000u) ? ~u : (u | 0x80000000u);
}

__device__ __forceinline__ float unsortable(unsigned u) {
    return (u & 0x80000000u) ? __uint_as_float(u & 0x7FFFFFFFu) : __uint_as_float(~u);
}

// Parallel "find threshold bin from top" over hist[NB]; all 512 threads call.
// Result: s_res[0]=T (bin), s_res[1]=G (count strictly above bin T).
template<int NB>
__device__ __forceinline__ void radix_sel(unsigned* hist, unsigned need,
                                          unsigned* s_res, unsigned* swsum) {
    const int per = NB >> 9;
    int tid = threadIdx.x;
    unsigned vals[per];
    unsigned part = 0;
    #pragma unroll
    for (int e = 0; e < per; ++e) {
        unsigned v = hist[NB - 1 - (tid * per + e)];   // high bins first
        vals[e] = v; part += v;
    }
    int lane = tid & 63, wv = tid >> 6;
    unsigned x = part;
    #pragma unroll
    for (int d = 1; d < 64; d <<= 1) {
        unsigned y = __shfl_up(x, d);
        if (lane >= d) x += y;
    }
    if (lane == 63) swsum[wv] = x;
    __syncthreads();
    unsigned woff = 0;
    for (int w = 0; w < wv; ++w) woff += swsum[w];
    unsigned run = woff + x - part;    // exclusive prefix (count in bins above)
    #pragma unroll
    for (int e = 0; e < per; ++e) {
        unsigned c = vals[e];
        if (run < need && run + c >= need) {
            s_res[0] = (unsigned)(NB - 1 - (tid * per + e));
            s_res[1] = run;
        }
        run += c;
    }
    __syncthreads();
}

// ============ FAST PATH ============

// K1a: 512 blocks (b*64 + chunk). Per-chunk LDS hist -> global hist[b][lvl].
__global__ __launch_bounds__(512) void topk_hist(const float* __restrict__ obj,
                                                 unsigned* __restrict__ hist) {
    int blk = blockIdx.x;
    int b = blk >> 6, c = blk & 63;
    int lvl = c < 48 ? 0 : c < 60 ? 1 : c < 63 ? 2 : 3;
    const float4* src = (const float4*)(obj + (size_t)b * A_TOTAL + (size_t)c * 4096);
    int n4c = (c == 63) ? 768 : 1024;
    __shared__ unsigned h[2048];
    int tid = threadIdx.x;
    for (int i = tid; i < 2048; i += 512) h[i] = 0;
    __syncthreads();
    for (int i4 = tid; i4 < n4c; i4 += 512) {
        float4 v = src[i4];
        atomicAdd(&h[sortable(v.x) >> 21], 1u);
        atomicAdd(&h[sortable(v.y) >> 21], 1u);
        atomicAdd(&h[sortable(v.z) >> 21], 1u);
        atomicAdd(&h[sortable(v.w) >> 21], 1u);
    }
    __syncthreads();
    unsigned* gh = hist + ((size_t)(b * 4 + lvl) << 11);
    for (int i = tid; i < 2048; i += 512) {
        unsigned cc = h[i];
        if (cc) atomicAdd(&gh[i], cc);
    }
}

// K1b: 32 blocks (b,lvl). Threshold bin T1 from hist.
__global__ __launch_bounds__(512) void topk_thresh(const unsigned* __restrict__ hist,
                                                   unsigned* __restrict__ t1arr) {
    __shared__ unsigned h[2048];
    __shared__ unsigned s_res[2];
    __shared__ unsigned swsum[8];
    int tid = threadIdx.x;
    for (int i = tid; i < 2048; i += 512) h[i] = hist[((size_t)blockIdx.x << 11) + i];
    __syncthreads();
    radix_sel<2048>(h, K_PER_LVL, s_res, swsum);
    if (tid == 0) t1arr[blockIdx.x] = s_res[0];
}

// K1c: 512 blocks. Two-phase scan: count + block prefix + ONE atomic per block
// per counter, then register-cached writes at reserved offsets. Order within
// sel is irrelevant (final sort ties break by unique anchor index).
__global__ __launch_bounds__(512) void topk_scan(const float* __restrict__ obj,
                                                 const unsigned* __restrict__ t1arr,
                                                 int* __restrict__ sel,
                                                 unsigned* __restrict__ gcnt,
                                                 unsigned* __restrict__ geq,
                                                 u64* __restrict__ gcand) {
    int blk = blockIdx.x;
    int b = blk >> 6, c = blk & 63;
    int lvl = c < 48 ? 0 : c < 60 ? 1 : c < 63 ? 2 : 3;
    const int offs[4] = {0, 196608, 245760, 258048};
    int off = offs[lvl];
    const float4* src = (const float4*)(obj + (size_t)b * A_TOTAL + (size_t)c * 4096);
    int n4c = (c == 63) ? 768 : 1024;
    int bl = b * 4 + lvl;
    unsigned T1 = t1arr[bl];
    int* out = sel + (size_t)bl * K_PER_LVL;
    u64* cand = gcand + (size_t)bl * CAND_CAP;
    int tid = threadIdx.x;
    int lane = tid & 63, wv = tid >> 6;
    int lbase = c * 4096 - off;          // chunk start, level-local
    __shared__ unsigned swsum1[8], swsum2[8];
    __shared__ unsigned s_base1, s_base2;

    // load (<=2 float4 per thread), keep in registers
    float4 va = src[tid];
    bool have2 = (tid + 512) < n4c;
    float4 vb = have2 ? src[tid + 512] : va;

    unsigned ka[4], kb[4];
    ka[0] = sortable(va.x); ka[1] = sortable(va.y);
    ka[2] = sortable(va.z); ka[3] = sortable(va.w);
    kb[0] = sortable(vb.x); kb[1] = sortable(vb.y);
    kb[2] = sortable(vb.z); kb[3] = sortable(vb.w);

    unsigned c1 = 0, c2 = 0;
    #pragma unroll
    for (int e = 0; e < 4; ++e) {
        unsigned bin = ka[e] >> 21;
        c1 += (bin > T1) ? 1u : 0u;
        c2 += (bin == T1) ? 1u : 0u;
    }
    if (have2) {
        #pragma unroll
        for (int e = 0; e < 4; ++e) {
            unsigned bin = kb[e] >> 21;
            c1 += (bin > T1) ? 1u : 0u;
            c2 += (bin == T1) ? 1u : 0u;
        }
    }

    // block exclusive prefix for c1 and c2
    unsigned x1 = c1, x2 = c2;
    #pragma unroll
    for (int d = 1; d < 64; d <<= 1) {
        unsigned y1 = __shfl_up(x1, d);
        unsigned y2 = __shfl_up(x2, d);
        if (lane >= d) { x1 += y1; x2 += y2; }
    }
    if (lane == 63) { swsum1[wv] = x1; swsum2[wv] = x2; }
    __syncthreads();
    unsigned woff1 = 0, woff2 = 0;
    for (int w = 0; w < wv; ++w) { woff1 += swsum1[w]; woff2 += swsum2[w]; }
    unsigned ex1 = woff1 + x1 - c1;
    unsigned ex2 = woff2 + x2 - c2;
    if (tid == 0) {
        unsigned t1t = 0, t2t = 0;
        for (int w = 0; w < 8; ++w) { t1t += swsum1[w]; t2t += swsum2[w]; }
        s_base1 = t1t ? atomicAdd(&gcnt[bl], t1t) : 0u;
        s_base2 = t2t ? atomicAdd(&geq[bl], t2t) : 0u;
    }
    __syncthreads();
    unsigned p1 = s_base1 + ex1;
    unsigned p2 = s_base2 + ex2;

    #pragma unroll
    for (int e = 0; e < 4; ++e) {
        unsigned k = ka[e];
        unsigned bin = k >> 21;
        int i = lbase + 4 * tid + e;
        if (bin > T1) { out[p1++] = off + i; }
        else if (bin == T1) {
            if (p2 < CAND_CAP)
                cand[p2] = (((u64)(k & 0x1FFFFFu)) << 18)
                         | (u64)(0x3FFFFu - (unsigned)i);
            p2++;
        }
    }
    if (have2) {
        #pragma unroll
        for (int e = 0; e < 4; ++e) {
            unsigned k = kb[e];
            unsigned bin = k >> 21;
            int i = lbase + 4 * (tid + 512) + e;
            if (bin > T1) { out[p1++] = off + i; }
            else if (bin == T1) {
                if (p2 < CAND_CAP)
                    cand[p2] = (((u64)(k & 0x1FFFFFu)) << 18)
                             | (u64)(0x3FFFFu - (unsigned)i);
                p2++;
            }
        }
    }
}

// K1d: 32 blocks. Exact top-m of boundary-bin candidates via 3x13-bit radix
// select on 39-bit unique keys; append at out[G1..].
__global__ __launch_bounds__(512) void topk_fin(const unsigned* __restrict__ hist,
                                                const unsigned* __restrict__ geq,
                                                const u64* __restrict__ gcand,
                                                int* __restrict__ sel) {
    int bl = blockIdx.x;
    const int offs[4] = {0, 196608, 245760, 258048};
    int off = offs[bl & 3];
    __shared__ unsigned h[8192];
    __shared__ u64 cand[CAND_CAP];
    __shared__ unsigned s_res[2];
    __shared__ unsigned swsum[8];
    __shared__ unsigned s_c2;
    int tid = threadIdx.x;

    for (int i = tid; i < 2048; i += 512) h[i] = hist[((size_t)bl << 11) + i];
    if (tid == 0) s_c2 = 0;
    __syncthreads();
    radix_sel<2048>(h, K_PER_LVL, s_res, swsum);
    unsigned G1 = s_res[1];
    int E = (int)min(geq[bl], (unsigned)CAND_CAP);
    const u64* gc = gcand + (size_t)bl * CAND_CAP;
    for (int e = tid; e < E; e += 512) cand[e] = gc[e];
    __syncthreads();
    unsigned m = K_PER_LVL - G1;

    // pass A: bits 38:26
    for (int i = tid; i < 8192; i += 512) h[i] = 0;
    __syncthreads();
    for (int e = tid; e < E; e += 512) atomicAdd(&h[(unsigned)(cand[e] >> 26)], 1u);
    __syncthreads();
    radix_sel<8192>(h, m, s_res, swsum);
    unsigned TA = s_res[0], GA = s_res[1];
    // pass B: bits 25:13 among prefix TA
    for (int i = tid; i < 8192; i += 512) h[i] = 0;
    __syncthreads();
    for (int e = tid; e < E; e += 512) {
        u64 ck = cand[e];
        if ((unsigned)(ck >> 26) == TA) atomicAdd(&h[(unsigned)(ck >> 13) & 0x1FFFu], 1u);
    }
    __syncthreads();
    radix_sel<8192>(h, m - GA, s_res, swsum);
    unsigned TB = s_res[0], GB = s_res[1];
    // pass C: bits 12:0 among prefix (TA,TB)
    for (int i = tid; i < 8192; i += 512) h[i] = 0;
    __syncthreads();
    unsigned pref26 = (TA << 13) | TB;
    for (int e = tid; e < E; e += 512) {
        u64 ck = cand[e];
        if ((unsigned)(ck >> 13) == pref26) atomicAdd(&h[(unsigned)ck & 0x1FFFu], 1u);
    }
    __syncthreads();
    radix_sel<8192>(h, m - GA - GB, s_res, swsum);
    unsigned TC = s_res[0];
    u64 KSTAR = (((u64)TA) << 26) | (((u64)TB) << 13) | (u64)TC;
    int* out = sel + (size_t)bl * K_PER_LVL;
    for (int e = tid; e < E; e += 512) {
        u64 ck = cand[e];
        if (ck >= KSTAR) {
            unsigned p = atomicAdd(&s_c2, 1u);
            out[G1 + p] = off + (int)(0x3FFFFu - (unsigned)(ck & 0x3FFFFu));
        }
    }
}

// K2a: decode slot SoA to scratch + standalone bitonic sort of own 512-key
// segment (LOCAL-index direction -> every segment fully DESCENDING).
// Grid 64: blockIdx = b*8 + seg.
__global__ __launch_bounds__(512) void decode_seg(const float* __restrict__ obj,
                                                  const float* __restrict__ deltas,
                                                  const float* __restrict__ anchors,
                                                  const int* __restrict__ sel,
                                                  u64* __restrict__ skey,
                                                  float* __restrict__ sx1, float* __restrict__ sy1,
                                                  float* __restrict__ sx2, float* __restrict__ sy2,
                                                  unsigned char* __restrict__ slv) {
    int b = blockIdx.x >> 3, seg = blockIdx.x & 7;
    int tid = threadIdx.x;
    __shared__ u64 kk[512];
    int s = (seg << 9) + tid;
    size_t base = (size_t)b * NSORT + s;

    if (s < K_TOTAL) {
        int g = sel[(size_t)b * K_TOTAL + s];
        float score = obj[(size_t)b * A_TOTAL + g];
        float4 dl = *(const float4*)(deltas + ((size_t)b * A_TOTAL + g) * 4);
        float4 an = *(const float4*)(anchors + (size_t)g * 4);
        float wa = an.z - an.x, ha = an.w - an.y;
        float cxa = an.x + 0.5f * wa, cya = an.y + 0.5f * ha;
        float dw = fminf(dl.z, BBOX_CLIP), dh = fminf(dl.w, BBOX_CLIP);
        float cx = dl.x * wa + cxa, cy = dl.y * ha + cya;
        float w = expf(dw) * wa, h = expf(dh) * ha;
        float x1 = cx - 0.5f * w, y1 = cy - 0.5f * h;
        float x2 = cx + 0.5f * w, y2 = cy + 0.5f * h;
        x1 = fminf(fmaxf(x1, 0.f), 1024.f);
        y1 = fminf(fmaxf(y1, 0.f), 1024.f);
        x2 = fminf(fmaxf(x2, 0.f), 1024.f);
        y2 = fminf(fmaxf(y2, 0.f), 1024.f);
        bool valid = (x2 - x1 >= 0.001f) && (y2 - y1 >= 0.001f) && (score >= 0.f);
        float sm = valid ? score : NEGV;
        int lv = (g >= 258048) ? 3 : (g >= 245760) ? 2 : (g >= 196608) ? 1 : 0;
        float lo = (float)lv * 1025.0f;
        sx1[base] = x1 + lo; sy1[base] = y1 + lo;
        sx2[base] = x2 + lo; sy2[base] = y2 + lo;
        slv[base] = (unsigned char)lv;
        kk[tid] = ((u64)sortable(sm) << 32)
                | ((u64)(0x3FFFFu - (unsigned)g) << 12)
                | (unsigned)s;
    } else {
        sx1[base] = 0.f; sy1[base] = 0.f; sx2[base] = 0.f; sy2[base] = 0.f;
        slv[base] = 0;
        kk[tid] = ((u64)sortable(NEGV) << 32) | (unsigned)s;
    }
    __syncthreads();

    for (int k = 2; k <= 512; k <<= 1) {
        for (int j = k >> 1; j > 0; j >>= 1) {
            int p = tid ^ j;
            if (p > tid) {
                u64 a = kk[tid], c = kk[p];
                bool up = (tid & k) == 0;      // LOCAL direction -> descending segment
                if (up ? (a < c) : (a > c)) { kk[tid] = c; kk[p] = a; }
            }
            __syncthreads();
        }
    }
    skey[base] = kk[tid];
}

// K2b: merge-path round. Merge pairs of descending lists of length L into 2L.
// Grid 64 (8 batches x 4096 elements / 512). Unique keys -> deterministic.
__global__ __launch_bounds__(512) void merge_round(const u64* __restrict__ src,
                                                   u64* __restrict__ dst, int L) {
    int e = blockIdx.x * 512 + threadIdx.x;   // 0..32767
    int b = e >> 12;
    int o = e & 4095;
    int twoL = L << 1;
    int q = o / twoL;
    int r = o - q * twoL;
    const u64* Sb = src + ((size_t)b << 12);
    const u64* A = Sb + q * twoL;
    const u64* Bl = A + L;
    u64 x; int pos;
    if (r < L) {
        x = A[r];
        int lo = 0, hi = L;
        while (lo < hi) { int mid = (lo + hi) >> 1; if (Bl[mid] > x) lo = mid + 1; else hi = mid; }
        pos = r + lo;                 // B elements > x precede x
    } else {
        int j = r - L;
        x = Bl[j];
        int lo = 0, hi = L;
        while (lo < hi) { int mid = (lo + hi) >> 1; if (A[mid] > x) lo = mid + 1; else hi = mid; }
        pos = j + lo;                 // A elements > x precede x
    }
    dst[((size_t)b << 12) + (size_t)(q * twoL + pos)] = x;
}

// K2c: gather slot SoA by sorted keys and emit sorted SoA + V. Grid 8.
__global__ __launch_bounds__(1024) void merge_emit(const u64* __restrict__ keysrc,
                                                   const float* __restrict__ sx1,
                                                   const float* __restrict__ sy1,
                                                   const float* __restrict__ sx2,
                                                   const float* __restrict__ sy2,
                                                   const unsigned char* __restrict__ slv,
                                                   float* __restrict__ gx1, float* __restrict__ gy1,
                                                   float* __restrict__ gx2, float* __restrict__ gy2,
                                                   float* __restrict__ gar, float* __restrict__ gsc,
                                                   unsigned char* __restrict__ glv,
                                                   int* __restrict__ gV) {
    int b = blockIdx.x;
    int tid = threadIdx.x;
    __shared__ int sV;
    if (tid == 0) sV = K_TOTAL;
    __syncthreads();
    size_t base = (size_t)b * NSORT;
    #pragma unroll
    for (int e = 0; e < 4; ++e) {
        int i = tid * 4 + e;
        u64 kv = keysrc[base + i];
        int slot = (int)(kv & 0xFFFull);
        float x1 = sx1[base + slot], y1 = sy1[base + slot];
        float x2 = sx2[base + slot], y2 = sy2[base + slot];
        gx1[base + i] = x1; gy1[base + i] = y1;
        gx2[base + i] = x2; gy2[base + i] = y2;
        gar[base + i] = (x2 - x1) * (y2 - y1);
        gsc[base + i] = unsortable((unsigned)(kv >> 32));
        glv[base + i] = slv[base + slot];
        if (i < K_TOTAL && (unsigned)(kv >> 32) < 0x80000000u) atomicMin(&sV, i);
    }
    __syncthreads();
    if (tid == 0) gV[b] = sV;
}

// K3: build triangular suppression bit-matrix, 2D triangle tiling, row+word ranged.
// Also ORs per-row nonzero into rowflag[b][64]. Gate lets later launches exit.
__global__ __launch_bounds__(512) void build_mat(const float* __restrict__ gx1,
                                                 const float* __restrict__ gy1,
                                                 const float* __restrict__ gx2,
                                                 const float* __restrict__ gy2,
                                                 const float* __restrict__ gar,
                                                 const int* __restrict__ gV,
                                                 u64* __restrict__ mat,
                                                 u64* __restrict__ rowflag,
                                                 int rt_start, int rt_count,
                                                 int wt_start, int wt_count,
                                                 const int* __restrict__ gate) {
    unsigned blk = blockIdx.x;
    int wt = wt_start + (int)(blk % (unsigned)wt_count);
    unsigned t = blk / (unsigned)wt_count;
    int b = (int)(t / (unsigned)rt_count);
    int rt = rt_start + (int)(t % (unsigned)rt_count);
    if (gate && gate[b]) return;
    int V = gV[b];
    int i0 = rt << 5;
    if (i0 >= V) return;
    int wbase = i0 >> 6;
    if (wt * 8 + 7 < wbase) return;    // tile fully below diagonal
    int tid = threadIdx.x, lane = tid & 63, wvi = tid >> 6;
    size_t base = (size_t)b * NSORT;

    __shared__ float rx1[32], ry1[32], rx2[32], ry2[32], rar[32];
    __shared__ u64 tile[32][8];
    __shared__ u64 rowor[32];

    int w = wt * 8 + wvi;              // this wave's word (<= 63)
    int j = (w << 6) + lane;
    float c1 = gx1[base + j], c2 = gy1[base + j];
    float c3 = gx2[base + j], c4 = gy2[base + j], ca = gar[base + j];

    if (tid < 32) {
        rx1[tid] = gx1[base + i0 + tid];
        ry1[tid] = gy1[base + i0 + tid];
        rx2[tid] = gx2[base + i0 + tid];
        ry2[tid] = gy2[base + i0 + tid];
        rar[tid] = gar[base + i0 + tid];
        rowor[tid] = 0ull;
    }
    __syncthreads();

    int rmax = min(32, V - i0);
    for (int r = 0; r < rmax; ++r) {
        int i = i0 + r;
        float ix1 = rx1[r], iy1 = ry1[r], ix2 = rx2[r], iy2 = ry2[r], ia = rar[r];
        float lx = fmaxf(ix1, c1);
        float ly = fmaxf(iy1, c2);
        float rx = fminf(ix2, c3);
        float ry = fminf(iy2, c4);
        float wx = fmaxf(rx - lx, 0.f), wy = fmaxf(ry - ly, 0.f);
        float inter = wx * wy;
        float iou = inter / (ia + ca - inter + 1e-9f);
        u64 bits = __ballot(iou > 0.7f && j > i);
        if (lane == 0) tile[r][wvi] = bits;
    }
    __syncthreads();

    // store 32 rows x 8 words (rows < rmax only); accumulate row-nonzero flags.
    if (tid < 256) {
        int r = tid >> 3, ww = tid & 7;
        if (r < rmax) {
            u64 v = tile[r][ww];
            mat[((size_t)b << 18) | ((size_t)(i0 + r) << 6) | (unsigned)(wt * 8 + ww)] = v;
            if (v) atomicOr(&rowor[r], v);
        }
    }
    __syncthreads();
    if (tid < 32 && tid < rmax && rowor[tid] != 0ull) {
        int i = i0 + tid;
        atomicOr(&rowflag[b * 64 + (i >> 6)], 1ull << (i & 63));
    }
}

// K4: phased greedy resolve with rowflag-gated fast paths.
// Phase 1 (gstart=0, glimit=20): only matrix words < 24 are valid; srem words
// >= 20 may absorb garbage but are never read when finishing within 20 groups.
// If not finished, phase 2 RESTARTS from group 0 with the fully-built matrix.
__global__ __launch_bounds__(512) void resolve_emit(const u64* __restrict__ mat,
                                                    const u64* __restrict__ rowflag,
                                                    const float* __restrict__ gx1,
                                                    const float* __restrict__ gy1,
                                                    const float* __restrict__ gx2,
                                                    const float* __restrict__ gy2,
                                                    const float* __restrict__ gsc,
                                                    const unsigned char* __restrict__ glv,
                                                    const int* __restrict__ gV,
                                                    int gstart, int glimit,
                                                    int* __restrict__ st_done,
                                                    int* __restrict__ st_kc,
                                                    u64* __restrict__ st_srem,
                                                    unsigned short* __restrict__ st_klist,
                                                    float* __restrict__ out_boxes,
                                                    float* __restrict__ out_scores) {
    int b = blockIdx.x;
    if (st_done[b]) return;            // earlier phase already emitted
    int tid = threadIdx.x;
    int lane = tid & 63, wvi = tid >> 6;
    __shared__ u64 srem[64];
    __shared__ u64 s_keptg;
    __shared__ int s_kc;
    __shared__ int s_done;
    int V = gV[b];
    int ngroups = (V + 63) >> 6;
    int gend = (glimit < ngroups) ? glimit : ngroups;
    const u64* M = mat + ((size_t)b << 18);
    unsigned short* kl = st_klist + (size_t)b * POST_N;

    if (tid < 64) srem[tid] = (gstart > 0) ? st_srem[b * 64 + tid] : 0ull;
    if (tid == 0) {
        s_kc = (gstart > 0) ? st_kc[b] : 0;
        s_done = (ngroups == 0) ? 1 : 0;
    }
    __syncthreads();

    for (int g = gstart; g < gend; ++g) {
        if (wvi == 0) {
            u64 gw = srem[g];
            int rem = V - (g << 6);
            u64 inmask = (rem >= 64) ? ~0ull : ((1ull << rem) - 1ull);
            u64 alive = ~gw & inmask;
            u64 gf = rowflag[b * 64 + g];
            u64 rw = 0ull;
            if ((alive & gf) != 0ull)
                rw = M[((size_t)((g << 6) + lane) << 6) + (unsigned)g];
            int kc0 = s_kc;
            int kc = kc0;
            u64 keptg = 0;
            bool me = ((alive >> lane) & 1ull) && ((rw & alive) != 0ull);
            if (__ballot(me) == 0ull) {
                // fast path: no in-group suppression possible -> keep all alive
                keptg = alive;
                if ((keptg >> lane) & 1ull) {
                    u64 lowmask = (1ull << lane) - 1ull;
                    int pos = kc0 + __popcll(keptg & lowmask);
                    if (pos < POST_N) kl[pos] = (unsigned short)((g << 6) + lane);
                }
                kc = kc0 + __popcll(keptg);
            } else {
                // exact greedy chain over alive rows
                u64 m = alive;
                while (m) {
                    int k = __ffsll((long long)m) - 1;
                    keptg |= 1ull << k;
                    if (lane == 0 && kc < POST_N) kl[kc] = (unsigned short)((g << 6) + k);
                    kc++;
                    if (kc >= POST_N) break;
                    u64 rk = __shfl(rw, k, 64);
                    m &= ~rk;
                    m &= ~(1ull << k);
                }
            }
            if (lane == 0) {
                s_kc = (kc > POST_N) ? POST_N : kc;
                s_keptg = keptg;
                if (kc >= POST_N || g + 1 >= ngroups) s_done = 1;
            }
        }
        __syncthreads();
        if (s_done) break;
        // cross-group suppression: only kept rows with nonzero rows (flagged)
        u64 keptg = s_keptg & rowflag[b * 64 + g];
        u64 acc = 0;
        int idx = 0;
        u64 m2 = keptg;
        while (m2) {
            int k = __ffsll((long long)m2) - 1; m2 &= m2 - 1;
            if ((idx & 7) == wvi) {
                u64 v = M[((size_t)((g << 6) + k) << 6) + (unsigned)lane];
                if (lane >= g) acc |= v;   // words < g may be stale (already-consumed groups)
            }
            idx++;
        }
        if (acc) atomicOr(&srem[lane], acc);
        __syncthreads();
    }
    __syncthreads();

    if (!s_done) {
        // boundary exit: phase 2 restarts from group 0 (no state needed)
        return;
    }

    int kcf = s_kc;
    if (tid == 0) st_done[b] = 1;

    float* ob = out_boxes + (size_t)b * POST_N * 4;
    float* os = out_scores + (size_t)b * POST_N;
    for (int q = tid; q < POST_N; q += 512) {
        ob[4 * q + 0] = 0.f; ob[4 * q + 1] = 0.f;
        ob[4 * q + 2] = 0.f; ob[4 * q + 3] = 0.f;
        os[q] = 0.f;
    }
    __syncthreads();
    size_t base = (size_t)b * NSORT;
    for (int p = tid; p < kcf; p += 512) {
        int i = kl[p];
        float lo = (float)glv[base + i] * 1025.0f;
        ob[4 * p + 0] = gx1[base + i] - lo;
        ob[4 * p + 1] = gy1[base + i] - lo;
        ob[4 * p + 2] = gx2[base + i] - lo;
        ob[4 * p + 3] = gy2[base + i] - lo;
        os[p] = gsc[base + i];
    }
}

extern "C" void kernel_launch(void* const* d_in, const int* in_sizes, int n_in,
                              void* d_out, int out_size, void* d_ws, size_t ws_size,
                              hipStream_t stream) {
    const float* obj     = (const float*)d_in[0];
    const float* deltas  = (const float*)d_in[1];
    const float* anchors = (const float*)d_in[2];
    float* out_boxes  = (float*)d_out;
    float* out_scores = (float*)d_out + B_BATCH * POST_N * 4;
    char* ws = (char*)d_ws;

    const size_t O_SEL   = 0;        // int[8][4000]           = 128000
    const size_t O_GCNT  = 128000;   // u32[32]
    const size_t O_GEQ   = 128128;   // u32[32]
    const size_t O_T1    = 128256;   // u32[32]  (ends 128384 < 131072)
    const size_t O_HIST  = 131072;   // u32[32][2048]          = 262144
    const size_t O_BX1   = 393216;   // f32[8][4096] each ↓    = 131072
    const size_t O_BY1   = 524288;
    const size_t O_BX2   = 655360;
    const size_t O_BY2   = 786432;
    const size_t O_BAR   = 917504;
    const size_t O_BSC   = 1048576;
    const size_t O_BLV   = 1179648;  // u8[8][4096]            = 32768
    const size_t O_BV    = 1212416;  // int[8]
    const size_t O_DONE  = 1212544;  // int[8]
    const size_t O_KC    = 1212608;  // int[8]
    const size_t O_SREM  = 1212672;  // u64[8][64]             = 4096
    const size_t O_KLIST = 1216768;  // u16[8][1000]           = 16000
    const size_t O_FLAG  = 1232768;  // u64[8][64]             = 4096
    // sort scratch in the hole before O_MAT (no aliasing with mat).
    // gcand (u64[32][3072] = 786432) reuses S_KEY..S_SY2: read by topk_fin
    // BEFORE decode_seg overwrites it (stream-ordered).
    const size_t S_KEY   = 1236864;  // u64[8][4096]           = 262144
    const size_t S_SX1   = 1499008;  // f32[8][4096] each ↓    = 131072
    const size_t S_SY1   = 1630080;
    const size_t S_SX2   = 1761152;
    const size_t S_SY2   = 1892224;
    const size_t S_SLV   = 2023296;  // u8[8][4096]            = 32768 (ends 2056064)
    const size_t O_CAND  = S_KEY;    // u64[32][3072]          = 786432 (ends 2023296)
    const size_t O_MAT   = 2097152;  // u64[8][4096][64]       = 16777216
    // merge ping-pong buf1 = head of O_MAT (mat written only AFTER merge_emit)
    const size_t S_KEY2  = O_MAT;    // u64[8][4096]           = 262144

    const int RT_SPLIT = 40;         // rows < 1280 built eagerly
    const int WT_SPLIT = 3;          // words < 24 built eagerly (covers groups < 20)

    hipMemsetAsync(ws + O_HIST, 0, 262144, stream);
    hipMemsetAsync(ws + O_GCNT, 0, 256, stream);
    hipMemsetAsync(ws + O_DONE, 0, (O_FLAG + 4096) - O_DONE, stream);
    topk_hist<<<512, 512, 0, stream>>>(obj, (unsigned*)(ws + O_HIST));
    topk_thresh<<<32, 512, 0, stream>>>((const unsigned*)(ws + O_HIST),
                                        (unsigned*)(ws + O_T1));
    topk_scan<<<512, 512, 0, stream>>>(obj, (const unsigned*)(ws + O_T1),
                                       (int*)(ws + O_SEL),
                                       (unsigned*)(ws + O_GCNT),
                                       (unsigned*)(ws + O_GEQ),
                                       (u64*)(ws + O_CAND));
    topk_fin<<<32, 512, 0, stream>>>((const unsigned*)(ws + O_HIST),
                                     (const unsigned*)(ws + O_GEQ),
                                     (const u64*)(ws + O_CAND),
                                     (int*)(ws + O_SEL));
    decode_seg<<<64, 512, 0, stream>>>(obj, deltas, anchors, (const int*)(ws + O_SEL),
                                       (u64*)(ws + S_KEY),
                                       (float*)(ws + S_SX1), (float*)(ws + S_SY1),
                                       (float*)(ws + S_SX2), (float*)(ws + S_SY2),
                                       (unsigned char*)(ws + S_SLV));
    merge_round<<<64, 512, 0, stream>>>((const u64*)(ws + S_KEY), (u64*)(ws + S_KEY2), 512);
    merge_round<<<64, 512, 0, stream>>>((const u64*)(ws + S_KEY2), (u64*)(ws + S_KEY), 1024);
    merge_round<<<64, 512, 0, stream>>>((const u64*)(ws + S_KEY), (u64*)(ws + S_KEY2), 2048);
    merge_emit<<<8, 1024, 0, stream>>>((const u64*)(ws + S_KEY2),
                                       (const float*)(ws + S_SX1), (const float*)(ws + S_SY1),
                                       (const float*)(ws + S_SX2), (const float*)(ws + S_SY2),
                                       (const unsigned char*)(ws + S_SLV),
                                       (float*)(ws + O_BX1), (float*)(ws + O_BY1),
                                       (float*)(ws + O_BX2), (float*)(ws + O_BY2),
                                       (float*)(ws + O_BAR), (float*)(ws + O_BSC),
                                       (unsigned char*)(ws + O_BLV), (int*)(ws + O_BV));
    // phase 1: rows < 1280, words < 24 only
    build_mat<<<B_BATCH * RT_SPLIT * WT_SPLIT, 512, 0, stream>>>(
        (const float*)(ws + O_BX1), (const float*)(ws + O_BY1),
        (const float*)(ws + O_BX2), (const float*)(ws + O_BY2),
        (const float*)(ws + O_BAR), (const int*)(ws + O_BV),
        (u64*)(ws + O_MAT), (u64*)(ws + O_FLAG),
        0, RT_SPLIT, 0, WT_SPLIT, (const int*)0);
    resolve_emit<<<8, 512, 0, stream>>>(
        (const u64*)(ws + O_MAT), (const u64*)(ws + O_FLAG),
        (const float*)(ws + O_BX1), (const float*)(ws + O_BY1),
        (const float*)(ws + O_BX2), (const float*)(ws + O_BY2),
        (const float*)(ws + O_BSC), (const unsigned char*)(ws + O_BLV),
        (const int*)(ws + O_BV), 0, RT_SPLIT / 2,
        (int*)(ws + O_DONE), (int*)(ws + O_KC),
        (u64*)(ws + O_SREM), (unsigned short*)(ws + O_KLIST),
        out_boxes, out_scores);
    // phase 2 (all gated; exit immediately when phase 1 finished)
    build_mat<<<B_BATCH * (128 - RT_SPLIT) * 8, 512, 0, stream>>>(
        (const float*)(ws + O_BX1), (const float*)(ws + O_BY1),
        (const float*)(ws + O_BX2), (const float*)(ws + O_BY2),
        (const float*)(ws + O_BAR), (const int*)(ws + O_BV),
        (u64*)(ws + O_MAT), (u64*)(ws + O_FLAG),
        RT_SPLIT, 128 - RT_SPLIT, 0, 8, (const int*)(ws + O_DONE));
    build_mat<<<B_BATCH * RT_SPLIT * (8 - WT_SPLIT), 512, 0, stream>>>(
        (const float*)(ws + O_BX1), (const float*)(ws + O_BY1),
        (const float*)(ws + O_BX2), (const float*)(ws + O_BY2),
        (const float*)(ws + O_BAR), (const int*)(ws + O_BV),
        (u64*)(ws + O_MAT), (u64*)(ws + O_FLAG),
        0, RT_SPLIT, WT_SPLIT, 8 - WT_SPLIT, (const int*)(ws + O_DONE));
    resolve_emit<<<8, 512, 0, stream>>>(
        (const u64*)(ws + O_MAT), (const u64*)(ws + O_FLAG),
        (const float*)(ws + O_BX1), (const float*)(ws + O_BY1),
        (const float*)(ws + O_BX2), (const float*)(ws + O_BY2),
        (const float*)(ws + O_BSC), (const unsigned char*)(ws + O_BLV),
        (const int*)(ws + O_BV), 0, 64,
        (int*)(ws + O_DONE), (int*)(ws + O_KC),
        (u64*)(ws + O_SREM), (unsigned short*)(ws + O_KLIST),
        out_boxes, out_scores);
}

// Round 25
// 123.141 us; speedup vs baseline: 1.8314x; 1.0255x over previous
//
#include <hip/hip_runtime.h>
#include <math.h>

#define A_TOTAL 261120
#define B_BATCH 8
#define K_PER_LVL 1000
#define K_TOTAL 4000
#define NSORT 4096
#define POST_N 1000
#define NEGV -1e30f
#define BBOX_CLIP 4.135166556742356f
#define CAND_CAP 3072

typedef unsigned long long u64;

__device__ __forceinline__ unsigned sortable(float f) {
    unsigned u = __float_as_uint(f);
    return (u & 0x80000000u) ? ~u : (u | 0x80000000u);
}

__device__ __forceinline__ float unsortable(unsigned u) {
    return (u & 0x80000000u) ? __uint_as_float(u & 0x7FFFFFFFu) : __uint_as_float(~u);
}

// Parallel "find threshold bin from top" over hist[NB]; all 512 threads call.
// Result: s_res[0]=T (bin), s_res[1]=G (count strictly above bin T).
template<int NB>
__device__ __forceinline__ void radix_sel(unsigned* hist, unsigned need,
                                          unsigned* s_res, unsigned* swsum) {
    const int per = NB >> 9;
    int tid = threadIdx.x;
    unsigned vals[per];
    unsigned part = 0;
    #pragma unroll
    for (int e = 0; e < per; ++e) {
        unsigned v = hist[NB - 1 - (tid * per + e)];   // high bins first
        vals[e] = v; part += v;
    }
    int lane = tid & 63, wv = tid >> 6;
    unsigned x = part;
    #pragma unroll
    for (int d = 1; d < 64; d <<= 1) {
        unsigned y = __shfl_up(x, d);
        if (lane >= d) x += y;
    }
    if (lane == 63) swsum[wv] = x;
    __syncthreads();
    unsigned woff = 0;
    for (int w = 0; w < wv; ++w) woff += swsum[w];
    unsigned run = woff + x - part;    // exclusive prefix (count in bins above)
    #pragma unroll
    for (int e = 0; e < per; ++e) {
        unsigned c = vals[e];
        if (run < need && run + c >= need) {
            s_res[0] = (unsigned)(NB - 1 - (tid * per + e));
            s_res[1] = run;
        }
        run += c;
    }
    __syncthreads();
}

// ============ FAST PATH ============

// K1a: 512 blocks (b*64 + chunk). Per-chunk LDS hist -> global hist[b][lvl].
__global__ __launch_bounds__(512) void topk_hist(const float* __restrict__ obj,
                                                 unsigned* __restrict__ hist) {
    int blk = blockIdx.x;
    int b = blk >> 6, c = blk & 63;
    int lvl = c < 48 ? 0 : c < 60 ? 1 : c < 63 ? 2 : 3;
    const float4* src = (const float4*)(obj + (size_t)b * A_TOTAL + (size_t)c * 4096);
    int n4c = (c == 63) ? 768 : 1024;
    __shared__ unsigned h[2048];
    int tid = threadIdx.x;
    for (int i = tid; i < 2048; i += 512) h[i] = 0;
    __syncthreads();
    for (int i4 = tid; i4 < n4c; i4 += 512) {
        float4 v = src[i4];
        atomicAdd(&h[sortable(v.x) >> 21], 1u);
        atomicAdd(&h[sortable(v.y) >> 21], 1u);
        atomicAdd(&h[sortable(v.z) >> 21], 1u);
        atomicAdd(&h[sortable(v.w) >> 21], 1u);
    }
    __syncthreads();
    unsigned* gh = hist + ((size_t)(b * 4 + lvl) << 11);
    for (int i = tid; i < 2048; i += 512) {
        unsigned cc = h[i];
        if (cc) atomicAdd(&gh[i], cc);
    }
}

// K1b: 32 blocks (b,lvl). Threshold bin T1 from hist.
__global__ __launch_bounds__(512) void topk_thresh(const unsigned* __restrict__ hist,
                                                   unsigned* __restrict__ t1arr) {
    __shared__ unsigned h[2048];
    __shared__ unsigned s_res[2];
    __shared__ unsigned swsum[8];
    int tid = threadIdx.x;
    for (int i = tid; i < 2048; i += 512) h[i] = hist[((size_t)blockIdx.x << 11) + i];
    __syncthreads();
    radix_sel<2048>(h, K_PER_LVL, s_res, swsum);
    if (tid == 0) t1arr[blockIdx.x] = s_res[0];
}

// K1c: 512 blocks. Two-phase scan: count + block prefix + ONE atomic per block
// per counter, then register-cached writes at reserved offsets. Order within
// sel is irrelevant (final sort ties break by unique anchor index).
__global__ __launch_bounds__(512) void topk_scan(const float* __restrict__ obj,
                                                 const unsigned* __restrict__ t1arr,
                                                 int* __restrict__ sel,
                                                 unsigned* __restrict__ gcnt,
                                                 unsigned* __restrict__ geq,
                                                 u64* __restrict__ gcand) {
    int blk = blockIdx.x;
    int b = blk >> 6, c = blk & 63;
    int lvl = c < 48 ? 0 : c < 60 ? 1 : c < 63 ? 2 : 3;
    const int offs[4] = {0, 196608, 245760, 258048};
    int off = offs[lvl];
    const float4* src = (const float4*)(obj + (size_t)b * A_TOTAL + (size_t)c * 4096);
    int n4c = (c == 63) ? 768 : 1024;
    int bl = b * 4 + lvl;
    unsigned T1 = t1arr[bl];
    int* out = sel + (size_t)bl * K_PER_LVL;
    u64* cand = gcand + (size_t)bl * CAND_CAP;
    int tid = threadIdx.x;
    int lane = tid & 63, wv = tid >> 6;
    int lbase = c * 4096 - off;          // chunk start, level-local
    __shared__ unsigned swsum1[8], swsum2[8];
    __shared__ unsigned s_base1, s_base2;

    // load (<=2 float4 per thread), keep in registers
    float4 va = src[tid];
    bool have2 = (tid + 512) < n4c;
    float4 vb = have2 ? src[tid + 512] : va;

    unsigned ka[4], kb[4];
    ka[0] = sortable(va.x); ka[1] = sortable(va.y);
    ka[2] = sortable(va.z); ka[3] = sortable(va.w);
    kb[0] = sortable(vb.x); kb[1] = sortable(vb.y);
    kb[2] = sortable(vb.z); kb[3] = sortable(vb.w);

    unsigned c1 = 0, c2 = 0;
    #pragma unroll
    for (int e = 0; e < 4; ++e) {
        unsigned bin = ka[e] >> 21;
        c1 += (bin > T1) ? 1u : 0u;
        c2 += (bin == T1) ? 1u : 0u;
    }
    if (have2) {
        #pragma unroll
        for (int e = 0; e < 4; ++e) {
            unsigned bin = kb[e] >> 21;
            c1 += (bin > T1) ? 1u : 0u;
            c2 += (bin == T1) ? 1u : 0u;
        }
    }

    // block exclusive prefix for c1 and c2
    unsigned x1 = c1, x2 = c2;
    #pragma unroll
    for (int d = 1; d < 64; d <<= 1) {
        unsigned y1 = __shfl_up(x1, d);
        unsigned y2 = __shfl_up(x2, d);
        if (lane >= d) { x1 += y1; x2 += y2; }
    }
    if (lane == 63) { swsum1[wv] = x1; swsum2[wv] = x2; }
    __syncthreads();
    unsigned woff1 = 0, woff2 = 0;
    for (int w = 0; w < wv; ++w) { woff1 += swsum1[w]; woff2 += swsum2[w]; }
    unsigned ex1 = woff1 + x1 - c1;
    unsigned ex2 = woff2 + x2 - c2;
    if (tid == 0) {
        unsigned t1t = 0, t2t = 0;
        for (int w = 0; w < 8; ++w) { t1t += swsum1[w]; t2t += swsum2[w]; }
        s_base1 = t1t ? atomicAdd(&gcnt[bl], t1t) : 0u;
        s_base2 = t2t ? atomicAdd(&geq[bl], t2t) : 0u;
    }
    __syncthreads();
    unsigned p1 = s_base1 + ex1;
    unsigned p2 = s_base2 + ex2;

    #pragma unroll
    for (int e = 0; e < 4; ++e) {
        unsigned k = ka[e];
        unsigned bin = k >> 21;
        int i = lbase + 4 * tid + e;
        if (bin > T1) { out[p1++] = off + i; }
        else if (bin == T1) {
            if (p2 < CAND_CAP)
                cand[p2] = (((u64)(k & 0x1FFFFFu)) << 18)
                         | (u64)(0x3FFFFu - (unsigned)i);
            p2++;
        }
    }
    if (have2) {
        #pragma unroll
        for (int e = 0; e < 4; ++e) {
            unsigned k = kb[e];
            unsigned bin = k >> 21;
            int i = lbase + 4 * (tid + 512) + e;
            if (bin > T1) { out[p1++] = off + i; }
            else if (bin == T1) {
                if (p2 < CAND_CAP)
                    cand[p2] = (((u64)(k & 0x1FFFFFu)) << 18)
                             | (u64)(0x3FFFFu - (unsigned)i);
                p2++;
            }
        }
    }
}

// K1d: 32 blocks. Exact top-m of boundary-bin candidates via 3x13-bit radix
// select on 39-bit unique keys; append at out[G1..].
__global__ __launch_bounds__(512) void topk_fin(const unsigned* __restrict__ hist,
                                                const unsigned* __restrict__ geq,
                                                const u64* __restrict__ gcand,
                                                int* __restrict__ sel) {
    int bl = blockIdx.x;
    const int offs[4] = {0, 196608, 245760, 258048};
    int off = offs[bl & 3];
    __shared__ unsigned h[8192];
    __shared__ u64 cand[CAND_CAP];
    __shared__ unsigned s_res[2];
    __shared__ unsigned swsum[8];
    __shared__ unsigned s_c2;
    int tid = threadIdx.x;

    for (int i = tid; i < 2048; i += 512) h[i] = hist[((size_t)bl << 11) + i];
    if (tid == 0) s_c2 = 0;
    __syncthreads();
    radix_sel<2048>(h, K_PER_LVL, s_res, swsum);
    unsigned G1 = s_res[1];
    int E = (int)min(geq[bl], (unsigned)CAND_CAP);
    const u64* gc = gcand + (size_t)bl * CAND_CAP;
    for (int e = tid; e < E; e += 512) cand[e] = gc[e];
    __syncthreads();
    unsigned m = K_PER_LVL - G1;

    // pass A: bits 38:26
    for (int i = tid; i < 8192; i += 512) h[i] = 0;
    __syncthreads();
    for (int e = tid; e < E; e += 512) atomicAdd(&h[(unsigned)(cand[e] >> 26)], 1u);
    __syncthreads();
    radix_sel<8192>(h, m, s_res, swsum);
    unsigned TA = s_res[0], GA = s_res[1];
    // pass B: bits 25:13 among prefix TA
    for (int i = tid; i < 8192; i += 512) h[i] = 0;
    __syncthreads();
    for (int e = tid; e < E; e += 512) {
        u64 ck = cand[e];
        if ((unsigned)(ck >> 26) == TA) atomicAdd(&h[(unsigned)(ck >> 13) & 0x1FFFu], 1u);
    }
    __syncthreads();
    radix_sel<8192>(h, m - GA, s_res, swsum);
    unsigned TB = s_res[0], GB = s_res[1];
    // pass C: bits 12:0 among prefix (TA,TB)
    for (int i = tid; i < 8192; i += 512) h[i] = 0;
    __syncthreads();
    unsigned pref26 = (TA << 13) | TB;
    for (int e = tid; e < E; e += 512) {
        u64 ck = cand[e];
        if ((unsigned)(ck >> 13) == pref26) atomicAdd(&h[(unsigned)ck & 0x1FFFu], 1u);
    }
    __syncthreads();
    radix_sel<8192>(h, m - GA - GB, s_res, swsum);
    unsigned TC = s_res[0];
    u64 KSTAR = (((u64)TA) << 26) | (((u64)TB) << 13) | (u64)TC;
    int* out = sel + (size_t)bl * K_PER_LVL;
    for (int e = tid; e < E; e += 512) {
        u64 ck = cand[e];
        if (ck >= KSTAR) {
            unsigned p = atomicAdd(&s_c2, 1u);
            out[G1 + p] = off + (int)(0x3FFFFu - (unsigned)(ck & 0x3FFFFu));
        }
    }
}

// K2a: decode slot SoA to scratch + standalone bitonic sort of own 512-key
// segment (LOCAL-index direction -> every segment fully DESCENDING).
// Grid 64: blockIdx = b*8 + seg.
__global__ __launch_bounds__(512) void decode_seg(const float* __restrict__ obj,
                                                  const float* __restrict__ deltas,
                                                  const float* __restrict__ anchors,
                                                  const int* __restrict__ sel,
                                                  u64* __restrict__ skey,
                                                  float* __restrict__ sx1, float* __restrict__ sy1,
                                                  float* __restrict__ sx2, float* __restrict__ sy2,
                                                  unsigned char* __restrict__ slv) {
    int b = blockIdx.x >> 3, seg = blockIdx.x & 7;
    int tid = threadIdx.x;
    __shared__ u64 kk[512];
    int s = (seg << 9) + tid;
    size_t base = (size_t)b * NSORT + s;

    if (s < K_TOTAL) {
        int g = sel[(size_t)b * K_TOTAL + s];
        float score = obj[(size_t)b * A_TOTAL + g];
        float4 dl = *(const float4*)(deltas + ((size_t)b * A_TOTAL + g) * 4);
        float4 an = *(const float4*)(anchors + (size_t)g * 4);
        float wa = an.z - an.x, ha = an.w - an.y;
        float cxa = an.x + 0.5f * wa, cya = an.y + 0.5f * ha;
        float dw = fminf(dl.z, BBOX_CLIP), dh = fminf(dl.w, BBOX_CLIP);
        float cx = dl.x * wa + cxa, cy = dl.y * ha + cya;
        float w = expf(dw) * wa, h = expf(dh) * ha;
        float x1 = cx - 0.5f * w, y1 = cy - 0.5f * h;
        float x2 = cx + 0.5f * w, y2 = cy + 0.5f * h;
        x1 = fminf(fmaxf(x1, 0.f), 1024.f);
        y1 = fminf(fmaxf(y1, 0.f), 1024.f);
        x2 = fminf(fmaxf(x2, 0.f), 1024.f);
        y2 = fminf(fmaxf(y2, 0.f), 1024.f);
        bool valid = (x2 - x1 >= 0.001f) && (y2 - y1 >= 0.001f) && (score >= 0.f);
        float sm = valid ? score : NEGV;
        int lv = (g >= 258048) ? 3 : (g >= 245760) ? 2 : (g >= 196608) ? 1 : 0;
        float lo = (float)lv * 1025.0f;
        sx1[base] = x1 + lo; sy1[base] = y1 + lo;
        sx2[base] = x2 + lo; sy2[base] = y2 + lo;
        slv[base] = (unsigned char)lv;
        kk[tid] = ((u64)sortable(sm) << 32)
                | ((u64)(0x3FFFFu - (unsigned)g) << 12)
                | (unsigned)s;
    } else {
        sx1[base] = 0.f; sy1[base] = 0.f; sx2[base] = 0.f; sy2[base] = 0.f;
        slv[base] = 0;
        kk[tid] = ((u64)sortable(NEGV) << 32) | (unsigned)s;
    }
    __syncthreads();

    for (int k = 2; k <= 512; k <<= 1) {
        for (int j = k >> 1; j > 0; j >>= 1) {
            int p = tid ^ j;
            if (p > tid) {
                u64 a = kk[tid], c = kk[p];
                bool up = (tid & k) == 0;      // LOCAL direction -> descending segment
                if (up ? (a < c) : (a > c)) { kk[tid] = c; kk[p] = a; }
            }
            __syncthreads();
        }
    }
    skey[base] = kk[tid];
}

// K2b: fused merge (3 merge-path rounds in LDS) + gather/emit. Grid 8, 1024 thr.
// Descending lists; unique keys -> deterministic, bit-identical to any sort.
__global__ __launch_bounds__(1024) void merge_all(const u64* __restrict__ skey,
                                                  const float* __restrict__ sx1,
                                                  const float* __restrict__ sy1,
                                                  const float* __restrict__ sx2,
                                                  const float* __restrict__ sy2,
                                                  const unsigned char* __restrict__ slv,
                                                  float* __restrict__ gx1, float* __restrict__ gy1,
                                                  float* __restrict__ gx2, float* __restrict__ gy2,
                                                  float* __restrict__ gar, float* __restrict__ gsc,
                                                  unsigned char* __restrict__ glv,
                                                  int* __restrict__ gV) {
    int b = blockIdx.x;
    int tid = threadIdx.x;
    __shared__ u64 k0[NSORT];
    __shared__ u64 k1[NSORT];
    __shared__ int sV;
    if (tid == 0) sV = K_TOTAL;
    size_t base = (size_t)b * NSORT;
    for (int i = tid; i < NSORT; i += 1024) k0[i] = skey[base + i];
    __syncthreads();

    // three merge-path rounds: L=512 (k0->k1), L=1024 (k1->k0), L=2048 (k0->k1)
    for (int rnd = 0; rnd < 3; ++rnd) {
        int L = 512 << rnd;
        const u64* src = (rnd == 1) ? k1 : k0;
        u64* dst = (rnd == 1) ? k0 : k1;
        int twoL = L << 1;
        #pragma unroll
        for (int e = 0; e < 4; ++e) {
            int o = tid * 4 + e;
            int q = o / twoL;
            int r = o - q * twoL;
            const u64* A = src + q * twoL;
            const u64* Bl = A + L;
            u64 x; int pos;
            if (r < L) {
                x = A[r];
                int lo = 0, hi = L;
                while (lo < hi) { int mid = (lo + hi) >> 1; if (Bl[mid] > x) lo = mid + 1; else hi = mid; }
                pos = r + lo;
            } else {
                int j = r - L;
                x = Bl[j];
                int lo = 0, hi = L;
                while (lo < hi) { int mid = (lo + hi) >> 1; if (A[mid] > x) lo = mid + 1; else hi = mid; }
                pos = j + lo;
            }
            dst[q * twoL + pos] = x;
        }
        __syncthreads();
        if (rnd == 1) {
            // copy back not needed: next round reads k0 (dst of rnd1)
        }
    }

    // final sorted keys in k1
    #pragma unroll
    for (int e = 0; e < 4; ++e) {
        int i = tid * 4 + e;
        u64 kv = k1[i];
        int slot = (int)(kv & 0xFFFull);
        float x1 = sx1[base + slot], y1 = sy1[base + slot];
        float x2 = sx2[base + slot], y2 = sy2[base + slot];
        gx1[base + i] = x1; gy1[base + i] = y1;
        gx2[base + i] = x2; gy2[base + i] = y2;
        gar[base + i] = (x2 - x1) * (y2 - y1);
        gsc[base + i] = unsortable((unsigned)(kv >> 32));
        glv[base + i] = slv[base + slot];
        if (i < K_TOTAL && (unsigned)(kv >> 32) < 0x80000000u) atomicMin(&sV, i);
    }
    __syncthreads();
    if (tid == 0) gV[b] = sV;
}

// K3: build triangular suppression bit-matrix, 2D triangle tiling, row+word ranged.
// Also ORs per-row nonzero into rowflag[b][64]. Gate lets later launches exit.
__global__ __launch_bounds__(512) void build_mat(const float* __restrict__ gx1,
                                                 const float* __restrict__ gy1,
                                                 const float* __restrict__ gx2,
                                                 const float* __restrict__ gy2,
                                                 const float* __restrict__ gar,
                                                 const int* __restrict__ gV,
                                                 u64* __restrict__ mat,
                                                 u64* __restrict__ rowflag,
                                                 int rt_start, int rt_count,
                                                 int wt_start, int wt_count,
                                                 const int* __restrict__ gate) {
    unsigned blk = blockIdx.x;
    int wt = wt_start + (int)(blk % (unsigned)wt_count);
    unsigned t = blk / (unsigned)wt_count;
    int b = (int)(t / (unsigned)rt_count);
    int rt = rt_start + (int)(t % (unsigned)rt_count);
    if (gate && gate[b]) return;
    int V = gV[b];
    int i0 = rt << 5;
    if (i0 >= V) return;
    int wbase = i0 >> 6;
    if (wt * 8 + 7 < wbase) return;    // tile fully below diagonal
    int tid = threadIdx.x, lane = tid & 63, wvi = tid >> 6;
    size_t base = (size_t)b * NSORT;

    __shared__ float rx1[32], ry1[32], rx2[32], ry2[32], rar[32];
    __shared__ u64 tile[32][8];
    __shared__ u64 rowor[32];

    int w = wt * 8 + wvi;              // this wave's word (<= 63)
    int j = (w << 6) + lane;
    float c1 = gx1[base + j], c2 = gy1[base + j];
    float c3 = gx2[base + j], c4 = gy2[base + j], ca = gar[base + j];

    if (tid < 32) {
        rx1[tid] = gx1[base + i0 + tid];
        ry1[tid] = gy1[base + i0 + tid];
        rx2[tid] = gx2[base + i0 + tid];
        ry2[tid] = gy2[base + i0 + tid];
        rar[tid] = gar[base + i0 + tid];
        rowor[tid] = 0ull;
    }
    __syncthreads();

    int rmax = min(32, V - i0);
    for (int r = 0; r < rmax; ++r) {
        int i = i0 + r;
        float ix1 = rx1[r], iy1 = ry1[r], ix2 = rx2[r], iy2 = ry2[r], ia = rar[r];
        float lx = fmaxf(ix1, c1);
        float ly = fmaxf(iy1, c2);
        float rx = fminf(ix2, c3);
        float ry = fminf(iy2, c4);
        float wx = fmaxf(rx - lx, 0.f), wy = fmaxf(ry - ly, 0.f);
        float inter = wx * wy;
        float iou = inter / (ia + ca - inter + 1e-9f);
        u64 bits = __ballot(iou > 0.7f && j > i);
        if (lane == 0) tile[r][wvi] = bits;
    }
    __syncthreads();

    // store 32 rows x 8 words (rows < rmax only); accumulate row-nonzero flags.
    if (tid < 256) {
        int r = tid >> 3, ww = tid & 7;
        if (r < rmax) {
            u64 v = tile[r][ww];
            mat[((size_t)b << 18) | ((size_t)(i0 + r) << 6) | (unsigned)(wt * 8 + ww)] = v;
            if (v) atomicOr(&rowor[r], v);
        }
    }
    __syncthreads();
    if (tid < 32 && tid < rmax && rowor[tid] != 0ull) {
        int i = i0 + tid;
        atomicOr(&rowflag[b * 64 + (i >> 6)], 1ull << (i & 63));
    }
}

// K4: phased greedy resolve with rowflag-gated fast paths.
// Phase 1 (gstart=0, glimit=20): only matrix words < 24 are valid; srem words
// >= 20 may absorb garbage but are never read when finishing within 20 groups.
// If not finished, phase 2 RESTARTS from group 0 with the fully-built matrix.
__global__ __launch_bounds__(512) void resolve_emit(const u64* __restrict__ mat,
                                                    const u64* __restrict__ rowflag,
                                                    const float* __restrict__ gx1,
                                                    const float* __restrict__ gy1,
                                                    const float* __restrict__ gx2,
                                                    const float* __restrict__ gy2,
                                                    const float* __restrict__ gsc,
                                                    const unsigned char* __restrict__ glv,
                                                    const int* __restrict__ gV,
                                                    int gstart, int glimit,
                                                    int* __restrict__ st_done,
                                                    int* __restrict__ st_kc,
                                                    u64* __restrict__ st_srem,
                                                    unsigned short* __restrict__ st_klist,
                                                    float* __restrict__ out_boxes,
                                                    float* __restrict__ out_scores) {
    int b = blockIdx.x;
    if (st_done[b]) return;            // earlier phase already emitted
    int tid = threadIdx.x;
    int lane = tid & 63, wvi = tid >> 6;
    __shared__ u64 srem[64];
    __shared__ u64 s_keptg;
    __shared__ int s_kc;
    __shared__ int s_done;
    int V = gV[b];
    int ngroups = (V + 63) >> 6;
    int gend = (glimit < ngroups) ? glimit : ngroups;
    const u64* M = mat + ((size_t)b << 18);
    unsigned short* kl = st_klist + (size_t)b * POST_N;

    if (tid < 64) srem[tid] = (gstart > 0) ? st_srem[b * 64 + tid] : 0ull;
    if (tid == 0) {
        s_kc = (gstart > 0) ? st_kc[b] : 0;
        s_done = (ngroups == 0) ? 1 : 0;
    }
    __syncthreads();

    for (int g = gstart; g < gend; ++g) {
        if (wvi == 0) {
            u64 gw = srem[g];
            int rem = V - (g << 6);
            u64 inmask = (rem >= 64) ? ~0ull : ((1ull << rem) - 1ull);
            u64 alive = ~gw & inmask;
            u64 gf = rowflag[b * 64 + g];
            u64 rw = 0ull;
            if ((alive & gf) != 0ull)
                rw = M[((size_t)((g << 6) + lane) << 6) + (unsigned)g];
            int kc0 = s_kc;
            int kc = kc0;
            u64 keptg = 0;
            bool me = ((alive >> lane) & 1ull) && ((rw & alive) != 0ull);
            if (__ballot(me) == 0ull) {
                // fast path: no in-group suppression possible -> keep all alive
                keptg = alive;
                if ((keptg >> lane) & 1ull) {
                    u64 lowmask = (1ull << lane) - 1ull;
                    int pos = kc0 + __popcll(keptg & lowmask);
                    if (pos < POST_N) kl[pos] = (unsigned short)((g << 6) + lane);
                }
                kc = kc0 + __popcll(keptg);
            } else {
                // exact greedy chain over alive rows
                u64 m = alive;
                while (m) {
                    int k = __ffsll((long long)m) - 1;
                    keptg |= 1ull << k;
                    if (lane == 0 && kc < POST_N) kl[kc] = (unsigned short)((g << 6) + k);
                    kc++;
                    if (kc >= POST_N) break;
                    u64 rk = __shfl(rw, k, 64);
                    m &= ~rk;
                    m &= ~(1ull << k);
                }
            }
            if (lane == 0) {
                s_kc = (kc > POST_N) ? POST_N : kc;
                s_keptg = keptg;
                if (kc >= POST_N || g + 1 >= ngroups) s_done = 1;
            }
        }
        __syncthreads();
        if (s_done) break;
        // cross-group suppression: only kept rows with nonzero rows (flagged)
        u64 keptg = s_keptg & rowflag[b * 64 + g];
        u64 acc = 0;
        int idx = 0;
        u64 m2 = keptg;
        while (m2) {
            int k = __ffsll((long long)m2) - 1; m2 &= m2 - 1;
            if ((idx & 7) == wvi) {
                u64 v = M[((size_t)((g << 6) + k) << 6) + (unsigned)lane];
                if (lane >= g) acc |= v;   // words < g may be stale (already-consumed groups)
            }
            idx++;
        }
        if (acc) atomicOr(&srem[lane], acc);
        __syncthreads();
    }
    __syncthreads();

    if (!s_done) {
        // boundary exit: phase 2 restarts from group 0 (no state needed)
        return;
    }

    int kcf = s_kc;
    if (tid == 0) st_done[b] = 1;

    float* ob = out_boxes + (size_t)b * POST_N * 4;
    float* os = out_scores + (size_t)b * POST_N;
    for (int q = tid; q < POST_N; q += 512) {
        ob[4 * q + 0] = 0.f; ob[4 * q + 1] = 0.f;
        ob[4 * q + 2] = 0.f; ob[4 * q + 3] = 0.f;
        os[q] = 0.f;
    }
    __syncthreads();
    size_t base = (size_t)b * NSORT;
    for (int p = tid; p < kcf; p += 512) {
        int i = kl[p];
        float lo = (float)glv[base + i] * 1025.0f;
        ob[4 * p + 0] = gx1[base + i] - lo;
        ob[4 * p + 1] = gy1[base + i] - lo;
        ob[4 * p + 2] = gx2[base + i] - lo;
        ob[4 * p + 3] = gy2[base + i] - lo;
        os[p] = gsc[base + i];
    }
}

extern "C" void kernel_launch(void* const* d_in, const int* in_sizes, int n_in,
                              void* d_out, int out_size, void* d_ws, size_t ws_size,
                              hipStream_t stream) {
    const float* obj     = (const float*)d_in[0];
    const float* deltas  = (const float*)d_in[1];
    const float* anchors = (const float*)d_in[2];
    float* out_boxes  = (float*)d_out;
    float* out_scores = (float*)d_out + B_BATCH * POST_N * 4;
    char* ws = (char*)d_ws;

    const size_t O_SEL   = 0;        // int[8][4000]           = 128000
    const size_t O_GCNT  = 128000;   // u32[32]
    const size_t O_GEQ   = 128128;   // u32[32]
    const size_t O_T1    = 128256;   // u32[32]  (ends 128384 < 131072)
    const size_t O_HIST  = 131072;   // u32[32][2048]          = 262144
    const size_t O_BX1   = 393216;   // f32[8][4096] each ↓    = 131072
    const size_t O_BY1   = 524288;
    const size_t O_BX2   = 655360;
    const size_t O_BY2   = 786432;
    const size_t O_BAR   = 917504;
    const size_t O_BSC   = 1048576;
    const size_t O_BLV   = 1179648;  // u8[8][4096]            = 32768
    const size_t O_BV    = 1212416;  // int[8]
    const size_t O_DONE  = 1212544;  // int[8]
    const size_t O_KC    = 1212608;  // int[8]
    const size_t O_SREM  = 1212672;  // u64[8][64]             = 4096
    const size_t O_KLIST = 1216768;  // u16[8][1000]           = 16000
    const size_t O_FLAG  = 1232768;  // u64[8][64]             = 4096
    // sort scratch in the hole before O_MAT (no aliasing with mat).
    // gcand (u64[32][3072] = 786432) reuses S_KEY..S_SY2: read by topk_fin
    // BEFORE decode_seg overwrites it (stream-ordered).
    const size_t S_KEY   = 1236864;  // u64[8][4096]           = 262144
    const size_t S_SX1   = 1499008;  // f32[8][4096] each ↓    = 131072
    const size_t S_SY1   = 1630080;
    const size_t S_SX2   = 1761152;
    const size_t S_SY2   = 1892224;
    const size_t S_SLV   = 2023296;  // u8[8][4096]            = 32768 (ends 2056064)
    const size_t O_CAND  = S_KEY;    // u64[32][3072]          = 786432 (ends 2023296)
    const size_t O_MAT   = 2097152;  // u64[8][4096][64]       = 16777216

    const int RT_SPLIT = 40;         // rows < 1280 built eagerly
    const int WT_SPLIT = 3;          // words < 24 built eagerly (covers groups < 20)

    hipMemsetAsync(ws + O_HIST, 0, 262144, stream);
    hipMemsetAsync(ws + O_GCNT, 0, 256, stream);
    hipMemsetAsync(ws + O_DONE, 0, (O_FLAG + 4096) - O_DONE, stream);
    topk_hist<<<512, 512, 0, stream>>>(obj, (unsigned*)(ws + O_HIST));
    topk_thresh<<<32, 512, 0, stream>>>((const unsigned*)(ws + O_HIST),
                                        (unsigned*)(ws + O_T1));
    topk_scan<<<512, 512, 0, stream>>>(obj, (const unsigned*)(ws + O_T1),
                                       (int*)(ws + O_SEL),
                                       (unsigned*)(ws + O_GCNT),
                                       (unsigned*)(ws + O_GEQ),
                                       (u64*)(ws + O_CAND));
    topk_fin<<<32, 512, 0, stream>>>((const unsigned*)(ws + O_HIST),
                                     (const unsigned*)(ws + O_GEQ),
                                     (const u64*)(ws + O_CAND),
                                     (int*)(ws + O_SEL));
    decode_seg<<<64, 512, 0, stream>>>(obj, deltas, anchors, (const int*)(ws + O_SEL),
                                       (u64*)(ws + S_KEY),
                                       (float*)(ws + S_SX1), (float*)(ws + S_SY1),
                                       (float*)(ws + S_SX2), (float*)(ws + S_SY2),
                                       (unsigned char*)(ws + S_SLV));
    merge_all<<<8, 1024, 0, stream>>>((const u64*)(ws + S_KEY),
                                      (const float*)(ws + S_SX1), (const float*)(ws + S_SY1),
                                      (const float*)(ws + S_SX2), (const float*)(ws + S_SY2),
                                      (const unsigned char*)(ws + S_SLV),
                                      (float*)(ws + O_BX1), (float*)(ws + O_BY1),
                                      (float*)(ws + O_BX2), (float*)(ws + O_BY2),
                                      (float*)(ws + O_BAR), (float*)(ws + O_BSC),
                                      (unsigned char*)(ws + O_BLV), (int*)(ws + O_BV));
    // phase 1: rows < 1280, words < 24 only
    build_mat<<<B_BATCH * RT_SPLIT * WT_SPLIT, 512, 0, stream>>>(
        (const float*)(ws + O_BX1), (const float*)(ws + O_BY1),
        (const float*)(ws + O_BX2), (const float*)(ws + O_BY2),
        (const float*)(ws + O_BAR), (const int*)(ws + O_BV),
        (u64*)(ws + O_MAT), (u64*)(ws + O_FLAG),
        0, RT_SPLIT, 0, WT_SPLIT, (const int*)0);
    resolve_emit<<<8, 512, 0, stream>>>(
        (const u64*)(ws + O_MAT), (const u64*)(ws + O_FLAG),
        (const float*)(ws + O_BX1), (const float*)(ws + O_BY1),
        (const float*)(ws + O_BX2), (const float*)(ws + O_BY2),
        (const float*)(ws + O_BSC), (const unsigned char*)(ws + O_BLV),
        (const int*)(ws + O_BV), 0, RT_SPLIT / 2,
        (int*)(ws + O_DONE), (int*)(ws + O_KC),
        (u64*)(ws + O_SREM), (unsigned short*)(ws + O_KLIST),
        out_boxes, out_scores);
    // phase 2 (all gated; exit immediately when phase 1 finished)
    build_mat<<<B_BATCH * (128 - RT_SPLIT) * 8, 512, 0, stream>>>(
        (const float*)(ws + O_BX1), (const float*)(ws + O_BY1),
        (const float*)(ws + O_BX2), (const float*)(ws + O_BY2),
        (const float*)(ws + O_BAR), (const int*)(ws + O_BV),
        (u64*)(ws + O_MAT), (u64*)(ws + O_FLAG),
        RT_SPLIT, 128 - RT_SPLIT, 0, 8, (const int*)(ws + O_DONE));
    build_mat<<<B_BATCH * RT_SPLIT * (8 - WT_SPLIT), 512, 0, stream>>>(
        (const float*)(ws + O_BX1), (const float*)(ws + O_BY1),
        (const float*)(ws + O_BX2), (const float*)(ws + O_BY2),
        (const float*)(ws + O_BAR), (const int*)(ws + O_BV),
        (u64*)(ws + O_MAT), (u64*)(ws + O_FLAG),
        0, RT_SPLIT, WT_SPLIT, 8 - WT_SPLIT, (const int*)(ws + O_DONE));
    resolve_emit<<<8, 512, 0, stream>>>(
        (const u64*)(ws + O_MAT), (const u64*)(ws + O_FLAG),
        (const float*)(ws + O_BX1), (const float*)(ws + O_BY1),
        (const float*)(ws + O_BX2), (const float*)(ws + O_BY2),
        (const float*)(ws + O_BSC), (const unsigned char*)(ws + O_BLV),
        (const int*)(ws + O_BV), 0, 64,
        (int*)(ws + O_DONE), (int*)(ws + O_KC),
        (u64*)(ws + O_SREM), (unsigned short*)(ws + O_KLIST),
        out_boxes, out_scores);
}

// Round 26
// 119.702 us; speedup vs baseline: 1.8840x; 1.0287x over previous
//
#include <hip/hip_runtime.h>
#include <math.h>

#define A_TOTAL 261120
#define B_BATCH 8
#define K_PER_LVL 1000
#define K_TOTAL 4000
#define NSORT 4096
#define POST_N 1000
#define NEGV -1e30f
#define BBOX_CLIP 4.135166556742356f
#define CAND_CAP 3072

typedef unsigned long long u64;

__device__ __forceinline__ unsigned sortable(float f) {
    unsigned u = __float_as_uint(f);
    return (u & 0x80000000u) ? ~u : (u | 0x80000000u);
}

__device__ __forceinline__ float unsortable(unsigned u) {
    return (u & 0x80000000u) ? __uint_as_float(u & 0x7FFFFFFFu) : __uint_as_float(~u);
}

// Parallel "find threshold bin from top" over hist[NB]; all 512 threads call.
// Result: s_res[0]=T (bin), s_res[1]=G (count strictly above bin T).
template<int NB>
__device__ __forceinline__ void radix_sel(unsigned* hist, unsigned need,
                                          unsigned* s_res, unsigned* swsum) {
    const int per = NB >> 9;
    int tid = threadIdx.x;
    unsigned vals[per];
    unsigned part = 0;
    #pragma unroll
    for (int e = 0; e < per; ++e) {
        unsigned v = hist[NB - 1 - (tid * per + e)];   // high bins first
        vals[e] = v; part += v;
    }
    int lane = tid & 63, wv = tid >> 6;
    unsigned x = part;
    #pragma unroll
    for (int d = 1; d < 64; d <<= 1) {
        unsigned y = __shfl_up(x, d);
        if (lane >= d) x += y;
    }
    if (lane == 63) swsum[wv] = x;
    __syncthreads();
    unsigned woff = 0;
    for (int w = 0; w < wv; ++w) woff += swsum[w];
    unsigned run = woff + x - part;    // exclusive prefix (count in bins above)
    #pragma unroll
    for (int e = 0; e < per; ++e) {
        unsigned c = vals[e];
        if (run < need && run + c >= need) {
            s_res[0] = (unsigned)(NB - 1 - (tid * per + e));
            s_res[1] = run;
        }
        run += c;
    }
    __syncthreads();
}

// ============ FAST PATH ============

// K1a: 512 blocks (b*64 + chunk). Per-chunk LDS hist -> global hist[b][lvl].
__global__ __launch_bounds__(512) void topk_hist(const float* __restrict__ obj,
                                                 unsigned* __restrict__ hist) {
    int blk = blockIdx.x;
    int b = blk >> 6, c = blk & 63;
    int lvl = c < 48 ? 0 : c < 60 ? 1 : c < 63 ? 2 : 3;
    const float4* src = (const float4*)(obj + (size_t)b * A_TOTAL + (size_t)c * 4096);
    int n4c = (c == 63) ? 768 : 1024;
    __shared__ unsigned h[2048];
    int tid = threadIdx.x;
    for (int i = tid; i < 2048; i += 512) h[i] = 0;
    __syncthreads();
    for (int i4 = tid; i4 < n4c; i4 += 512) {
        float4 v = src[i4];
        atomicAdd(&h[sortable(v.x) >> 21], 1u);
        atomicAdd(&h[sortable(v.y) >> 21], 1u);
        atomicAdd(&h[sortable(v.z) >> 21], 1u);
        atomicAdd(&h[sortable(v.w) >> 21], 1u);
    }
    __syncthreads();
    unsigned* gh = hist + ((size_t)(b * 4 + lvl) << 11);
    for (int i = tid; i < 2048; i += 512) {
        unsigned cc = h[i];
        if (cc) atomicAdd(&gh[i], cc);
    }
}

// K1b: 32 blocks (b,lvl). Threshold bin T1 from hist + clear per-call state
// (gcnt/geq/done/rowflag) before downstream consumers (stream-ordered).
__global__ __launch_bounds__(512) void topk_thresh(const unsigned* __restrict__ hist,
                                                   unsigned* __restrict__ t1arr,
                                                   unsigned* __restrict__ gcnt,
                                                   unsigned* __restrict__ geq,
                                                   int* __restrict__ st_done,
                                                   u64* __restrict__ rowflag) {
    __shared__ unsigned h[2048];
    __shared__ unsigned s_res[2];
    __shared__ unsigned swsum[8];
    int tid = threadIdx.x;
    int bl = blockIdx.x;
    for (int i = tid; i < 2048; i += 512) h[i] = hist[((size_t)bl << 11) + i];
    if (tid < 16) rowflag[bl * 16 + tid] = 0ull;   // 32 blocks x 16 = 512 u64
    if (tid == 0) {
        gcnt[bl] = 0u;
        geq[bl] = 0u;
        if ((bl & 3) == 0) st_done[bl >> 2] = 0;
    }
    __syncthreads();
    radix_sel<2048>(h, K_PER_LVL, s_res, swsum);
    if (tid == 0) t1arr[bl] = s_res[0];
}

// K1c: 512 blocks. Two-phase scan: count + block prefix + ONE atomic per block
// per counter, then register-cached writes at reserved offsets. Order within
// sel is irrelevant (final sort ties break by unique anchor index).
__global__ __launch_bounds__(512) void topk_scan(const float* __restrict__ obj,
                                                 const unsigned* __restrict__ t1arr,
                                                 int* __restrict__ sel,
                                                 unsigned* __restrict__ gcnt,
                                                 unsigned* __restrict__ geq,
                                                 u64* __restrict__ gcand) {
    int blk = blockIdx.x;
    int b = blk >> 6, c = blk & 63;
    int lvl = c < 48 ? 0 : c < 60 ? 1 : c < 63 ? 2 : 3;
    const int offs[4] = {0, 196608, 245760, 258048};
    int off = offs[lvl];
    const float4* src = (const float4*)(obj + (size_t)b * A_TOTAL + (size_t)c * 4096);
    int n4c = (c == 63) ? 768 : 1024;
    int bl = b * 4 + lvl;
    unsigned T1 = t1arr[bl];
    int* out = sel + (size_t)bl * K_PER_LVL;
    u64* cand = gcand + (size_t)bl * CAND_CAP;
    int tid = threadIdx.x;
    int lane = tid & 63, wv = tid >> 6;
    int lbase = c * 4096 - off;          // chunk start, level-local
    __shared__ unsigned swsum1[8], swsum2[8];
    __shared__ unsigned s_base1, s_base2;

    // load (<=2 float4 per thread), keep in registers
    float4 va = src[tid];
    bool have2 = (tid + 512) < n4c;
    float4 vb = have2 ? src[tid + 512] : va;

    unsigned ka[4], kb[4];
    ka[0] = sortable(va.x); ka[1] = sortable(va.y);
    ka[2] = sortable(va.z); ka[3] = sortable(va.w);
    kb[0] = sortable(vb.x); kb[1] = sortable(vb.y);
    kb[2] = sortable(vb.z); kb[3] = sortable(vb.w);

    unsigned c1 = 0, c2 = 0;
    #pragma unroll
    for (int e = 0; e < 4; ++e) {
        unsigned bin = ka[e] >> 21;
        c1 += (bin > T1) ? 1u : 0u;
        c2 += (bin == T1) ? 1u : 0u;
    }
    if (have2) {
        #pragma unroll
        for (int e = 0; e < 4; ++e) {
            unsigned bin = kb[e] >> 21;
            c1 += (bin > T1) ? 1u : 0u;
            c2 += (bin == T1) ? 1u : 0u;
        }
    }

    // block exclusive prefix for c1 and c2
    unsigned x1 = c1, x2 = c2;
    #pragma unroll
    for (int d = 1; d < 64; d <<= 1) {
        unsigned y1 = __shfl_up(x1, d);
        unsigned y2 = __shfl_up(x2, d);
        if (lane >= d) { x1 += y1; x2 += y2; }
    }
    if (lane == 63) { swsum1[wv] = x1; swsum2[wv] = x2; }
    __syncthreads();
    unsigned woff1 = 0, woff2 = 0;
    for (int w = 0; w < wv; ++w) { woff1 += swsum1[w]; woff2 += swsum2[w]; }
    unsigned ex1 = woff1 + x1 - c1;
    unsigned ex2 = woff2 + x2 - c2;
    if (tid == 0) {
        unsigned t1t = 0, t2t = 0;
        for (int w = 0; w < 8; ++w) { t1t += swsum1[w]; t2t += swsum2[w]; }
        s_base1 = t1t ? atomicAdd(&gcnt[bl], t1t) : 0u;
        s_base2 = t2t ? atomicAdd(&geq[bl], t2t) : 0u;
    }
    __syncthreads();
    unsigned p1 = s_base1 + ex1;
    unsigned p2 = s_base2 + ex2;

    #pragma unroll
    for (int e = 0; e < 4; ++e) {
        unsigned k = ka[e];
        unsigned bin = k >> 21;
        int i = lbase + 4 * tid + e;
        if (bin > T1) { out[p1++] = off + i; }
        else if (bin == T1) {
            if (p2 < CAND_CAP)
                cand[p2] = (((u64)(k & 0x1FFFFFu)) << 18)
                         | (u64)(0x3FFFFu - (unsigned)i);
            p2++;
        }
    }
    if (have2) {
        #pragma unroll
        for (int e = 0; e < 4; ++e) {
            unsigned k = kb[e];
            unsigned bin = k >> 21;
            int i = lbase + 4 * (tid + 512) + e;
            if (bin > T1) { out[p1++] = off + i; }
            else if (bin == T1) {
                if (p2 < CAND_CAP)
                    cand[p2] = (((u64)(k & 0x1FFFFFu)) << 18)
                             | (u64)(0x3FFFFu - (unsigned)i);
                p2++;
            }
        }
    }
}

// K1d: 32 blocks. Exact top-m of boundary-bin candidates via 3x13-bit radix
// select on 39-bit unique keys; append at out[G1..].
__global__ __launch_bounds__(512) void topk_fin(const unsigned* __restrict__ hist,
                                                const unsigned* __restrict__ geq,
                                                const u64* __restrict__ gcand,
                                                int* __restrict__ sel) {
    int bl = blockIdx.x;
    const int offs[4] = {0, 196608, 245760, 258048};
    int off = offs[bl & 3];
    __shared__ unsigned h[8192];
    __shared__ u64 cand[CAND_CAP];
    __shared__ unsigned s_res[2];
    __shared__ unsigned swsum[8];
    __shared__ unsigned s_c2;
    int tid = threadIdx.x;

    for (int i = tid; i < 2048; i += 512) h[i] = hist[((size_t)bl << 11) + i];
    if (tid == 0) s_c2 = 0;
    __syncthreads();
    radix_sel<2048>(h, K_PER_LVL, s_res, swsum);
    unsigned G1 = s_res[1];
    int E = (int)min(geq[bl], (unsigned)CAND_CAP);
    const u64* gc = gcand + (size_t)bl * CAND_CAP;
    for (int e = tid; e < E; e += 512) cand[e] = gc[e];
    __syncthreads();
    unsigned m = K_PER_LVL - G1;

    // pass A: bits 38:26
    for (int i = tid; i < 8192; i += 512) h[i] = 0;
    __syncthreads();
    for (int e = tid; e < E; e += 512) atomicAdd(&h[(unsigned)(cand[e] >> 26)], 1u);
    __syncthreads();
    radix_sel<8192>(h, m, s_res, swsum);
    unsigned TA = s_res[0], GA = s_res[1];
    // pass B: bits 25:13 among prefix TA
    for (int i = tid; i < 8192; i += 512) h[i] = 0;
    __syncthreads();
    for (int e = tid; e < E; e += 512) {
        u64 ck = cand[e];
        if ((unsigned)(ck >> 26) == TA) atomicAdd(&h[(unsigned)(ck >> 13) & 0x1FFFu], 1u);
    }
    __syncthreads();
    radix_sel<8192>(h, m - GA, s_res, swsum);
    unsigned TB = s_res[0], GB = s_res[1];
    // pass C: bits 12:0 among prefix (TA,TB)
    for (int i = tid; i < 8192; i += 512) h[i] = 0;
    __syncthreads();
    unsigned pref26 = (TA << 13) | TB;
    for (int e = tid; e < E; e += 512) {
        u64 ck = cand[e];
        if ((unsigned)(ck >> 13) == pref26) atomicAdd(&h[(unsigned)ck & 0x1FFFu], 1u);
    }
    __syncthreads();
    radix_sel<8192>(h, m - GA - GB, s_res, swsum);
    unsigned TC = s_res[0];
    u64 KSTAR = (((u64)TA) << 26) | (((u64)TB) << 13) | (u64)TC;
    int* out = sel + (size_t)bl * K_PER_LVL;
    for (int e = tid; e < E; e += 512) {
        u64 ck = cand[e];
        if (ck >= KSTAR) {
            unsigned p = atomicAdd(&s_c2, 1u);
            out[G1 + p] = off + (int)(0x3FFFFu - (unsigned)(ck & 0x3FFFFu));
        }
    }
}

// K2a: decode slot SoA to scratch + standalone bitonic sort of own 512-key
// segment (LOCAL-index direction -> every segment fully DESCENDING).
// Grid 64: blockIdx = b*8 + seg.
__global__ __launch_bounds__(512) void decode_seg(const float* __restrict__ obj,
                                                  const float* __restrict__ deltas,
                                                  const float* __restrict__ anchors,
                                                  const int* __restrict__ sel,
                                                  u64* __restrict__ skey,
                                                  float* __restrict__ sx1, float* __restrict__ sy1,
                                                  float* __restrict__ sx2, float* __restrict__ sy2,
                                                  unsigned char* __restrict__ slv) {
    int b = blockIdx.x >> 3, seg = blockIdx.x & 7;
    int tid = threadIdx.x;
    __shared__ u64 kk[512];
    int s = (seg << 9) + tid;
    size_t base = (size_t)b * NSORT + s;

    if (s < K_TOTAL) {
        int g = sel[(size_t)b * K_TOTAL + s];
        float score = obj[(size_t)b * A_TOTAL + g];
        float4 dl = *(const float4*)(deltas + ((size_t)b * A_TOTAL + g) * 4);
        float4 an = *(const float4*)(anchors + (size_t)g * 4);
        float wa = an.z - an.x, ha = an.w - an.y;
        float cxa = an.x + 0.5f * wa, cya = an.y + 0.5f * ha;
        float dw = fminf(dl.z, BBOX_CLIP), dh = fminf(dl.w, BBOX_CLIP);
        float cx = dl.x * wa + cxa, cy = dl.y * ha + cya;
        float w = expf(dw) * wa, h = expf(dh) * ha;
        float x1 = cx - 0.5f * w, y1 = cy - 0.5f * h;
        float x2 = cx + 0.5f * w, y2 = cy + 0.5f * h;
        x1 = fminf(fmaxf(x1, 0.f), 1024.f);
        y1 = fminf(fmaxf(y1, 0.f), 1024.f);
        x2 = fminf(fmaxf(x2, 0.f), 1024.f);
        y2 = fminf(fmaxf(y2, 0.f), 1024.f);
        bool valid = (x2 - x1 >= 0.001f) && (y2 - y1 >= 0.001f) && (score >= 0.f);
        float sm = valid ? score : NEGV;
        int lv = (g >= 258048) ? 3 : (g >= 245760) ? 2 : (g >= 196608) ? 1 : 0;
        float lo = (float)lv * 1025.0f;
        sx1[base] = x1 + lo; sy1[base] = y1 + lo;
        sx2[base] = x2 + lo; sy2[base] = y2 + lo;
        slv[base] = (unsigned char)lv;
        kk[tid] = ((u64)sortable(sm) << 32)
                | ((u64)(0x3FFFFu - (unsigned)g) << 12)
                | (unsigned)s;
    } else {
        sx1[base] = 0.f; sy1[base] = 0.f; sx2[base] = 0.f; sy2[base] = 0.f;
        slv[base] = 0;
        kk[tid] = ((u64)sortable(NEGV) << 32) | (unsigned)s;
    }
    __syncthreads();

    for (int k = 2; k <= 512; k <<= 1) {
        for (int j = k >> 1; j > 0; j >>= 1) {
            int p = tid ^ j;
            if (p > tid) {
                u64 a = kk[tid], c = kk[p];
                bool up = (tid & k) == 0;      // LOCAL direction -> descending segment
                if (up ? (a < c) : (a > c)) { kk[tid] = c; kk[p] = a; }
            }
            __syncthreads();
        }
    }
    skey[base] = kk[tid];
}

// K2b: fused merge (3 merge-path rounds in LDS) + gather/emit. Grid 8, 1024 thr.
// Descending lists; unique keys -> deterministic, bit-identical to any sort.
__global__ __launch_bounds__(1024) void merge_all(const u64* __restrict__ skey,
                                                  const float* __restrict__ sx1,
                                                  const float* __restrict__ sy1,
                                                  const float* __restrict__ sx2,
                                                  const float* __restrict__ sy2,
                                                  const unsigned char* __restrict__ slv,
                                                  float* __restrict__ gx1, float* __restrict__ gy1,
                                                  float* __restrict__ gx2, float* __restrict__ gy2,
                                                  float* __restrict__ gar, float* __restrict__ gsc,
                                                  unsigned char* __restrict__ glv,
                                                  int* __restrict__ gV) {
    int b = blockIdx.x;
    int tid = threadIdx.x;
    __shared__ u64 k0[NSORT];
    __shared__ u64 k1[NSORT];
    __shared__ int sV;
    if (tid == 0) sV = K_TOTAL;
    size_t base = (size_t)b * NSORT;
    for (int i = tid; i < NSORT; i += 1024) k0[i] = skey[base + i];
    __syncthreads();

    // three merge-path rounds: L=512 (k0->k1), L=1024 (k1->k0), L=2048 (k0->k1)
    for (int rnd = 0; rnd < 3; ++rnd) {
        int L = 512 << rnd;
        const u64* src = (rnd == 1) ? k1 : k0;
        u64* dst = (rnd == 1) ? k0 : k1;
        int twoL = L << 1;
        #pragma unroll
        for (int e = 0; e < 4; ++e) {
            int o = tid * 4 + e;
            int q = o / twoL;
            int r = o - q * twoL;
            const u64* A = src + q * twoL;
            const u64* Bl = A + L;
            u64 x; int pos;
            if (r < L) {
                x = A[r];
                int lo = 0, hi = L;
                while (lo < hi) { int mid = (lo + hi) >> 1; if (Bl[mid] > x) lo = mid + 1; else hi = mid; }
                pos = r + lo;
            } else {
                int j = r - L;
                x = Bl[j];
                int lo = 0, hi = L;
                while (lo < hi) { int mid = (lo + hi) >> 1; if (A[mid] > x) lo = mid + 1; else hi = mid; }
                pos = j + lo;
            }
            dst[q * twoL + pos] = x;
        }
        __syncthreads();
    }

    // final sorted keys in k1
    #pragma unroll
    for (int e = 0; e < 4; ++e) {
        int i = tid * 4 + e;
        u64 kv = k1[i];
        int slot = (int)(kv & 0xFFFull);
        float x1 = sx1[base + slot], y1 = sy1[base + slot];
        float x2 = sx2[base + slot], y2 = sy2[base + slot];
        gx1[base + i] = x1; gy1[base + i] = y1;
        gx2[base + i] = x2; gy2[base + i] = y2;
        gar[base + i] = (x2 - x1) * (y2 - y1);
        gsc[base + i] = unsortable((unsigned)(kv >> 32));
        glv[base + i] = slv[base + slot];
        if (i < K_TOTAL && (unsigned)(kv >> 32) < 0x80000000u) atomicMin(&sV, i);
    }
    __syncthreads();
    if (tid == 0) gV[b] = sV;
}

// K3: build triangular suppression bit-matrix, 2D triangle tiling, row+word ranged.
// Also ORs per-row nonzero into rowflag[b][64]. Gate lets later launches exit.
__global__ __launch_bounds__(512) void build_mat(const float* __restrict__ gx1,
                                                 const float* __restrict__ gy1,
                                                 const float* __restrict__ gx2,
                                                 const float* __restrict__ gy2,
                                                 const float* __restrict__ gar,
                                                 const int* __restrict__ gV,
                                                 u64* __restrict__ mat,
                                                 u64* __restrict__ rowflag,
                                                 int rt_start, int rt_count,
                                                 int wt_start, int wt_count,
                                                 const int* __restrict__ gate) {
    unsigned blk = blockIdx.x;
    int wt = wt_start + (int)(blk % (unsigned)wt_count);
    unsigned t = blk / (unsigned)wt_count;
    int b = (int)(t / (unsigned)rt_count);
    int rt = rt_start + (int)(t % (unsigned)rt_count);
    if (gate && gate[b]) return;
    int V = gV[b];
    int i0 = rt << 5;
    if (i0 >= V) return;
    int wbase = i0 >> 6;
    if (wt * 8 + 7 < wbase) return;    // tile fully below diagonal
    int tid = threadIdx.x, lane = tid & 63, wvi = tid >> 6;
    size_t base = (size_t)b * NSORT;

    __shared__ float rx1[32], ry1[32], rx2[32], ry2[32], rar[32];
    __shared__ u64 tile[32][8];
    __shared__ u64 rowor[32];

    int w = wt * 8 + wvi;              // this wave's word (<= 63)
    int j = (w << 6) + lane;
    float c1 = gx1[base + j], c2 = gy1[base + j];
    float c3 = gx2[base + j], c4 = gy2[base + j], ca = gar[base + j];

    if (tid < 32) {
        rx1[tid] = gx1[base + i0 + tid];
        ry1[tid] = gy1[base + i0 + tid];
        rx2[tid] = gx2[base + i0 + tid];
        ry2[tid] = gy2[base + i0 + tid];
        rar[tid] = gar[base + i0 + tid];
        rowor[tid] = 0ull;
    }
    __syncthreads();

    int rmax = min(32, V - i0);
    for (int r = 0; r < rmax; ++r) {
        int i = i0 + r;
        float ix1 = rx1[r], iy1 = ry1[r], ix2 = rx2[r], iy2 = ry2[r], ia = rar[r];
        float lx = fmaxf(ix1, c1);
        float ly = fmaxf(iy1, c2);
        float rx = fminf(ix2, c3);
        float ry = fminf(iy2, c4);
        float wx = fmaxf(rx - lx, 0.f), wy = fmaxf(ry - ly, 0.f);
        float inter = wx * wy;
        float iou = inter / (ia + ca - inter + 1e-9f);
        u64 bits = __ballot(iou > 0.7f && j > i);
        if (lane == 0) tile[r][wvi] = bits;
    }
    __syncthreads();

    // store 32 rows x 8 words (rows < rmax only); accumulate row-nonzero flags.
    if (tid < 256) {
        int r = tid >> 3, ww = tid & 7;
        if (r < rmax) {
            u64 v = tile[r][ww];
            mat[((size_t)b << 18) | ((size_t)(i0 + r) << 6) | (unsigned)(wt * 8 + ww)] = v;
            if (v) atomicOr(&rowor[r], v);
        }
    }
    __syncthreads();
    if (tid < 32 && tid < rmax && rowor[tid] != 0ull) {
        int i = i0 + tid;
        atomicOr(&rowflag[b * 64 + (i >> 6)], 1ull << (i & 63));
    }
}

// K4: phased greedy resolve with rowflag-gated fast paths.
// Phase 1 (gstart=0, glimit=20): only matrix words < 24 are valid; srem words
// >= 20 may absorb garbage but are never read when finishing within 20 groups.
// If not finished, phase 2 RESTARTS from group 0 with the fully-built matrix.
__global__ __launch_bounds__(512) void resolve_emit(const u64* __restrict__ mat,
                                                    const u64* __restrict__ rowflag,
                                                    const float* __restrict__ gx1,
                                                    const float* __restrict__ gy1,
                                                    const float* __restrict__ gx2,
                                                    const float* __restrict__ gy2,
                                                    const float* __restrict__ gsc,
                                                    const unsigned char* __restrict__ glv,
                                                    const int* __restrict__ gV,
                                                    int gstart, int glimit,
                                                    int* __restrict__ st_done,
                                                    int* __restrict__ st_kc,
                                                    u64* __restrict__ st_srem,
                                                    unsigned short* __restrict__ st_klist,
                                                    float* __restrict__ out_boxes,
                                                    float* __restrict__ out_scores) {
    int b = blockIdx.x;
    if (st_done[b]) return;            // earlier phase already emitted
    int tid = threadIdx.x;
    int lane = tid & 63, wvi = tid >> 6;
    __shared__ u64 srem[64];
    __shared__ u64 s_keptg;
    __shared__ int s_kc;
    __shared__ int s_done;
    int V = gV[b];
    int ngroups = (V + 63) >> 6;
    int gend = (glimit < ngroups) ? glimit : ngroups;
    const u64* M = mat + ((size_t)b << 18);
    unsigned short* kl = st_klist + (size_t)b * POST_N;

    if (tid < 64) srem[tid] = (gstart > 0) ? st_srem[b * 64 + tid] : 0ull;
    if (tid == 0) {
        s_kc = (gstart > 0) ? st_kc[b] : 0;
        s_done = (ngroups == 0) ? 1 : 0;
    }
    __syncthreads();

    for (int g = gstart; g < gend; ++g) {
        if (wvi == 0) {
            u64 gw = srem[g];
            int rem = V - (g << 6);
            u64 inmask = (rem >= 64) ? ~0ull : ((1ull << rem) - 1ull);
            u64 alive = ~gw & inmask;
            u64 gf = rowflag[b * 64 + g];
            u64 rw = 0ull;
            if ((alive & gf) != 0ull)
                rw = M[((size_t)((g << 6) + lane) << 6) + (unsigned)g];
            int kc0 = s_kc;
            int kc = kc0;
            u64 keptg = 0;
            bool me = ((alive >> lane) & 1ull) && ((rw & alive) != 0ull);
            if (__ballot(me) == 0ull) {
                // fast path: no in-group suppression possible -> keep all alive
                keptg = alive;
                if ((keptg >> lane) & 1ull) {
                    u64 lowmask = (1ull << lane) - 1ull;
                    int pos = kc0 + __popcll(keptg & lowmask);
                    if (pos < POST_N) kl[pos] = (unsigned short)((g << 6) + lane);
                }
                kc = kc0 + __popcll(keptg);
            } else {
                // exact greedy chain over alive rows
                u64 m = alive;
                while (m) {
                    int k = __ffsll((long long)m) - 1;
                    keptg |= 1ull << k;
                    if (lane == 0 && kc < POST_N) kl[kc] = (unsigned short)((g << 6) + k);
                    kc++;
                    if (kc >= POST_N) break;
                    u64 rk = __shfl(rw, k, 64);
                    m &= ~rk;
                    m &= ~(1ull << k);
                }
            }
            if (lane == 0) {
                s_kc = (kc > POST_N) ? POST_N : kc;
                s_keptg = keptg;
                if (kc >= POST_N || g + 1 >= ngroups) s_done = 1;
            }
        }
        __syncthreads();
        if (s_done) break;
        // cross-group suppression: only kept rows with nonzero rows (flagged)
        u64 keptg = s_keptg & rowflag[b * 64 + g];
        u64 acc = 0;
        int idx = 0;
        u64 m2 = keptg;
        while (m2) {
            int k = __ffsll((long long)m2) - 1; m2 &= m2 - 1;
            if ((idx & 7) == wvi) {
                u64 v = M[((size_t)((g << 6) + k) << 6) + (unsigned)lane];
                if (lane >= g) acc |= v;   // words < g may be stale (already-consumed groups)
            }
            idx++;
        }
        if (acc) atomicOr(&srem[lane], acc);
        __syncthreads();
    }
    __syncthreads();

    if (!s_done) {
        // boundary exit: phase 2 restarts from group 0 (no state needed)
        return;
    }

    int kcf = s_kc;
    if (tid == 0) st_done[b] = 1;

    float* ob = out_boxes + (size_t)b * POST_N * 4;
    float* os = out_scores + (size_t)b * POST_N;
    for (int q = tid; q < POST_N; q += 512) {
        ob[4 * q + 0] = 0.f; ob[4 * q + 1] = 0.f;
        ob[4 * q + 2] = 0.f; ob[4 * q + 3] = 0.f;
        os[q] = 0.f;
    }
    __syncthreads();
    size_t base = (size_t)b * NSORT;
    for (int p = tid; p < kcf; p += 512) {
        int i = kl[p];
        float lo = (float)glv[base + i] * 1025.0f;
        ob[4 * p + 0] = gx1[base + i] - lo;
        ob[4 * p + 1] = gy1[base + i] - lo;
        ob[4 * p + 2] = gx2[base + i] - lo;
        ob[4 * p + 3] = gy2[base + i] - lo;
        os[p] = gsc[base + i];
    }
}

extern "C" void kernel_launch(void* const* d_in, const int* in_sizes, int n_in,
                              void* d_out, int out_size, void* d_ws, size_t ws_size,
                              hipStream_t stream) {
    const float* obj     = (const float*)d_in[0];
    const float* deltas  = (const float*)d_in[1];
    const float* anchors = (const float*)d_in[2];
    float* out_boxes  = (float*)d_out;
    float* out_scores = (float*)d_out + B_BATCH * POST_N * 4;
    char* ws = (char*)d_ws;

    const size_t O_SEL   = 0;        // int[8][4000]           = 128000
    const size_t O_GCNT  = 128000;   // u32[32]
    const size_t O_GEQ   = 128128;   // u32[32]
    const size_t O_T1    = 128256;   // u32[32]  (ends 128384 < 131072)
    const size_t O_HIST  = 131072;   // u32[32][2048]          = 262144
    const size_t O_BX1   = 393216;   // f32[8][4096] each ↓    = 131072
    const size_t O_BY1   = 524288;
    const size_t O_BX2   = 655360;
    const size_t O_BY2   = 786432;
    const size_t O_BAR   = 917504;
    const size_t O_BSC   = 1048576;
    const size_t O_BLV   = 1179648;  // u8[8][4096]            = 32768
    const size_t O_BV    = 1212416;  // int[8]
    const size_t O_DONE  = 1212544;  // int[8]
    const size_t O_KC    = 1212608;  // int[8]
    const size_t O_SREM  = 1212672;  // u64[8][64]             = 4096
    const size_t O_KLIST = 1216768;  // u16[8][1000]           = 16000
    const size_t O_FLAG  = 1232768;  // u64[8][64]             = 4096
    // sort scratch in the hole before O_MAT (no aliasing with mat).
    // gcand (u64[32][3072] = 786432) reuses S_KEY..S_SY2: read by topk_fin
    // BEFORE decode_seg overwrites it (stream-ordered).
    const size_t S_KEY   = 1236864;  // u64[8][4096]           = 262144
    const size_t S_SX1   = 1499008;  // f32[8][4096] each ↓    = 131072
    const size_t S_SY1   = 1630080;
    const size_t S_SX2   = 1761152;
    const size_t S_SY2   = 1892224;
    const size_t S_SLV   = 2023296;  // u8[8][4096]            = 32768 (ends 2056064)
    const size_t O_CAND  = S_KEY;    // u64[32][3072]          = 786432 (ends 2023296)
    const size_t O_MAT   = 2097152;  // u64[8][4096][64]       = 16777216

    const int RT_SPLIT = 40;         // rows < 1280 built eagerly
    const int WT_SPLIT = 3;          // words < 24 built eagerly (covers groups < 20)

    hipMemsetAsync(ws + O_HIST, 0, 262144, stream);
    topk_hist<<<512, 512, 0, stream>>>(obj, (unsigned*)(ws + O_HIST));
    topk_thresh<<<32, 512, 0, stream>>>((const unsigned*)(ws + O_HIST),
                                        (unsigned*)(ws + O_T1),
                                        (unsigned*)(ws + O_GCNT),
                                        (unsigned*)(ws + O_GEQ),
                                        (int*)(ws + O_DONE),
                                        (u64*)(ws + O_FLAG));
    topk_scan<<<512, 512, 0, stream>>>(obj, (const unsigned*)(ws + O_T1),
                                       (int*)(ws + O_SEL),
                                       (unsigned*)(ws + O_GCNT),
                                       (unsigned*)(ws + O_GEQ),
                                       (u64*)(ws + O_CAND));
    topk_fin<<<32, 512, 0, stream>>>((const unsigned*)(ws + O_HIST),
                                     (const unsigned*)(ws + O_GEQ),
                                     (const u64*)(ws + O_CAND),
                                     (int*)(ws + O_SEL));
    decode_seg<<<64, 512, 0, stream>>>(obj, deltas, anchors, (const int*)(ws + O_SEL),
                                       (u64*)(ws + S_KEY),
                                       (float*)(ws + S_SX1), (float*)(ws + S_SY1),
                                       (float*)(ws + S_SX2), (float*)(ws + S_SY2),
                                       (unsigned char*)(ws + S_SLV));
    merge_all<<<8, 1024, 0, stream>>>((const u64*)(ws + S_KEY),
                                      (const float*)(ws + S_SX1), (const float*)(ws + S_SY1),
                                      (const float*)(ws + S_SX2), (const float*)(ws + S_SY2),
                                      (const unsigned char*)(ws + S_SLV),
                                      (float*)(ws + O_BX1), (float*)(ws + O_BY1),
                                      (float*)(ws + O_BX2), (float*)(ws + O_BY2),
                                      (float*)(ws + O_BAR), (float*)(ws + O_BSC),
                                      (unsigned char*)(ws + O_BLV), (int*)(ws + O_BV));
    // phase 1: rows < 1280, words < 24 only
    build_mat<<<B_BATCH * RT_SPLIT * WT_SPLIT, 512, 0, stream>>>(
        (const float*)(ws + O_BX1), (const float*)(ws + O_BY1),
        (const float*)(ws + O_BX2), (const float*)(ws + O_BY2),
        (const float*)(ws + O_BAR), (const int*)(ws + O_BV),
        (u64*)(ws + O_MAT), (u64*)(ws + O_FLAG),
        0, RT_SPLIT, 0, WT_SPLIT, (const int*)0);
    resolve_emit<<<8, 512, 0, stream>>>(
        (const u64*)(ws + O_MAT), (const u64*)(ws + O_FLAG),
        (const float*)(ws + O_BX1), (const float*)(ws + O_BY1),
        (const float*)(ws + O_BX2), (const float*)(ws + O_BY2),
        (const float*)(ws + O_BSC), (const unsigned char*)(ws + O_BLV),
        (const int*)(ws + O_BV), 0, RT_SPLIT / 2,
        (int*)(ws + O_DONE), (int*)(ws + O_KC),
        (u64*)(ws + O_SREM), (unsigned short*)(ws + O_KLIST),
        out_boxes, out_scores);
    // phase 2 (all gated; exit immediately when phase 1 finished)
    build_mat<<<B_BATCH * (128 - RT_SPLIT) * 8, 512, 0, stream>>>(
        (const float*)(ws + O_BX1), (const float*)(ws + O_BY1),
        (const float*)(ws + O_BX2), (const float*)(ws + O_BY2),
        (const float*)(ws + O_BAR), (const int*)(ws + O_BV),
        (u64*)(ws + O_MAT), (u64*)(ws + O_FLAG),
        RT_SPLIT, 128 - RT_SPLIT, 0, 8, (const int*)(ws + O_DONE));
    build_mat<<<B_BATCH * RT_SPLIT * (8 - WT_SPLIT), 512, 0, stream>>>(
        (const float*)(ws + O_BX1), (const float*)(ws + O_BY1),
        (const float*)(ws + O_BX2), (const float*)(ws + O_BY2),
        (const float*)(ws + O_BAR), (const int*)(ws + O_BV),
        (u64*)(ws + O_MAT), (u64*)(ws + O_FLAG),
        0, RT_SPLIT, WT_SPLIT, 8 - WT_SPLIT, (const int*)(ws + O_DONE));
    resolve_emit<<<8, 512, 0, stream>>>(
        (const u64*)(ws + O_MAT), (const u64*)(ws + O_FLAG),
        (const float*)(ws + O_BX1), (const float*)(ws + O_BY1),
        (const float*)(ws + O_BX2), (const float*)(ws + O_BY2),
        (const float*)(ws + O_BSC), (const unsigned char*)(ws + O_BLV),
        (const int*)(ws + O_BV), 0, 64,
        (int*)(ws + O_DONE), (int*)(ws + O_KC),
        (u64*)(ws + O_SREM), (unsigned short*)(ws + O_KLIST),
        out_boxes, out_scores);
}